// Round 4
// baseline (20112.920 us; speedup 1.0000x reference)
//
#include <hip/hip_runtime.h>

#define NND 100000   // nodes
#define NED 400000   // edges
#define FEAT 143
#define EDIM 6
#define H 128
#define NG 4096      // graphs
#define NBS 391      // ceil(NND/256)

__device__ __forceinline__ float lk(float v){ return v >= 0.f ? v : 0.01f*v; }
__device__ __forceinline__ float eluf(float v){ return v > 0.f ? v : __expf(v) - 1.f; }
__device__ __forceinline__ float sgm(float v){ return 1.f/(1.f + __expf(-v)); }
__device__ __forceinline__ float wsum(float v){
  #pragma unroll
  for(int o=32;o>0;o>>=1) v += __shfl_xor(v,o);
  return v;
}
__device__ __forceinline__ float wmax(float v){
  #pragma unroll
  for(int o=32;o>0;o>>=1) v = fmaxf(v, __shfl_xor(v,o));
  return v;
}

// ---------------- CSR build (counting sort of edges by dst) ----------------
__global__ __launch_bounds__(256) void k_hist(const int* __restrict__ ei, int* __restrict__ deg){
  int e = blockIdx.x*256 + threadIdx.x;
  if (e < NED) atomicAdd(&deg[ei[NED + e]], 1);
}
__global__ __launch_bounds__(256) void k_scan1(const int* __restrict__ deg, int* __restrict__ off, int* __restrict__ bsum){
  __shared__ int s[256];
  int i = blockIdx.x*256 + threadIdx.x;
  int v = (i < NND) ? deg[i] : 0;
  s[threadIdx.x] = v; __syncthreads();
  for(int o=1;o<256;o<<=1){
    int t = 0; if (threadIdx.x >= o) t = s[threadIdx.x - o];
    __syncthreads(); s[threadIdx.x] += t; __syncthreads();
  }
  if (i < NND) off[i] = s[threadIdx.x] - v;       // block-local exclusive
  if (threadIdx.x == 255) bsum[blockIdx.x] = s[255];
}
__global__ __launch_bounds__(512) void k_scan2(int* __restrict__ bsum){
  __shared__ int s[512];
  int t = threadIdx.x;
  int v = (t < NBS) ? bsum[t] : 0;
  s[t] = v; __syncthreads();
  for(int o=1;o<512;o<<=1){
    int x = 0; if (t >= o) x = s[t - o];
    __syncthreads(); s[t] += x; __syncthreads();
  }
  if (t < NBS) bsum[t] = s[t] - v;                // exclusive
  if (t == 511) bsum[NBS] = s[511];               // total = NED
}
__global__ __launch_bounds__(256) void k_scan3(int* __restrict__ off, const int* __restrict__ bsum, int* __restrict__ cursor){
  int i = blockIdx.x*256 + threadIdx.x;
  if (i < NND){
    int v = off[i] + bsum[blockIdx.x];
    off[i] = v; cursor[i] = v;
  }
  if (i == 0) off[NND] = bsum[NBS];
}
__global__ __launch_bounds__(256) void k_scatter(const int* __restrict__ ei, int* __restrict__ cursor, int* __restrict__ perm){
  int e = blockIdx.x*256 + threadIdx.x;
  if (e < NED){
    int p = atomicAdd(&cursor[ei[NED + e]], 1);
    perm[p] = e;
  }
}
__global__ __launch_bounds__(256) void k_gstart(const int* __restrict__ batch, int* __restrict__ goff){
  int i = blockIdx.x*256 + threadIdx.x;
  if (i >= NND) return;
  int bi = batch[i];
  int bp = (i > 0) ? batch[i-1] : -1;
  for(int g = bp+1; g <= bi; g++) goff[g] = i;
  if (i == NND-1) for(int g = bi+1; g <= NG; g++) goff[g] = NND;
}

// ---------------- VALU GEMM: C[M,128] = act(A[M,K] @ W[:,:K]^T + bias) ----------------
template<bool BIAS, int ACT>
__global__ __launch_bounds__(256) void k_vgemm(const float* __restrict__ A, int lda, int K,
        const float* __restrict__ W, int ldw,
        const float* __restrict__ bias, float* __restrict__ C, int M)
{
  int wave = threadIdx.x >> 6, lane = threadIdx.x & 63;
  int r = blockIdx.x*4 + wave;
  if (r >= M) return;
  const float* ar = A + (size_t)r*lda;
  float a0 = (lane       < K) ? ar[lane]       : 0.f;
  float a1 = (lane +  64 < K) ? ar[lane + 64]  : 0.f;
  float a2 = (lane + 128 < K) ? ar[lane + 128] : 0.f;
  #pragma unroll
  for(int slot=0; slot<2; slot++){
    float v = 0.f;
    for(int j=0;j<64;j++){
      int n = slot*64 + j;
      const float* wr = W + (size_t)n*ldw;
      float w0 = (lane       < K) ? wr[lane]       : 0.f;
      float w1 = (lane +  64 < K) ? wr[lane + 64]  : 0.f;
      float w2 = (lane + 128 < K) ? wr[lane + 128] : 0.f;
      float p = a0*w0 + a1*w1 + a2*w2;
      p = wsum(p);
      if (j == lane) v = p;
    }
    int col = slot*64 + lane;
    if (BIAS) v += bias[col];
    if (ACT == 1) v = lk(v);
    C[(size_t)r*H + col] = v;
  }
}

// ---------------- VALU GRU cell: Out = relu(gru(Xin, Hid)), one wave per row ----------------
__global__ __launch_bounds__(256) void k_vgru(const float* __restrict__ Xin,
      const float* __restrict__ Hid, float* __restrict__ Out,
      const float* __restrict__ Wi, const float* __restrict__ Wh,
      const float* __restrict__ bi, const float* __restrict__ bh, int M)
{
  int wave = threadIdx.x >> 6, lane = threadIdx.x & 63;
  int r = blockIdx.x*4 + wave;
  if (r >= M) return;
  float xi0 = Xin[(size_t)r*H + lane], xi1 = Xin[(size_t)r*H + lane + 64];
  float hi0 = Hid[(size_t)r*H + lane], hi1 = Hid[(size_t)r*H + lane + 64];
  float giv[6], ghv[6];                       // index gs = n>>6 = g*2 + slot
  #pragma unroll
  for(int gs=0; gs<6; gs++){
    float vi = 0.f, vh = 0.f;
    for(int j=0;j<64;j++){
      int n = gs*64 + j;
      const float* wi = Wi + (size_t)n*H;
      const float* wh = Wh + (size_t)n*H;
      float pi = xi0*wi[lane] + xi1*wi[lane+64];
      float ph = hi0*wh[lane] + hi1*wh[lane+64];
      pi = wsum(pi); ph = wsum(ph);
      if (j == lane){ vi = pi + bi[n]; vh = ph + bh[n]; }
    }
    giv[gs] = vi; ghv[gs] = vh;
  }
  #pragma unroll
  for(int slot=0; slot<2; slot++){
    float rg = sgm(giv[0+slot] + ghv[0+slot]);
    float zg = sgm(giv[2+slot] + ghv[2+slot]);
    float ng = tanhf(giv[4+slot] + rg*ghv[4+slot]);
    float hv = slot ? hi1 : hi0;
    float o = (1.f - zg)*ng + zg*hv;
    Out[(size_t)r*H + slot*64 + lane] = fmaxf(o, 0.f);
  }
}

// ---------------- row dot products: o[n] = A[n,:] . v  (all fp32) ----------------
template<bool TWO>
__global__ __launch_bounds__(256) void k_rowdot(const float* __restrict__ A,
    const float* __restrict__ v1, const float* __restrict__ v2,
    float* __restrict__ o1, float* __restrict__ o2, int M)
{
  int idx = blockIdx.x*4 + (threadIdx.x >> 6);
  if (idx >= M) return;
  int lane = threadIdx.x & 63;
  int h0 = lane*2;
  float a0 = A[(size_t)idx*H + h0];
  float a1 = A[(size_t)idx*H + h0 + 1];
  float p1 = a0*v1[h0] + a1*v1[h0+1];
  p1 = wsum(p1);
  if (lane == 0) o1[idx] = p1;
  if (TWO){
    float p2 = a0*v2[h0] + a1*v2[h0+1];
    p2 = wsum(p2);
    if (lane == 0) o2[idx] = p2;
  }
}

// ---------------- GATEConv edge attention + aggregation (wave per dst node) ----------------
__device__ __forceinline__ float gate_araw(int e, int h0,
    const int* __restrict__ ei, const float* __restrict__ eattr,
    const float* __restrict__ u, const float* W1e_s, const float* attl_s, float rn)
{
  int s = ei[e];
  float u0 = u[(size_t)s*H + h0];
  float u1 = u[(size_t)s*H + h0 + 1];
  const float* ep = eattr + (size_t)e*EDIM;
  float v0 = 0.f, v1 = 0.f;
  #pragma unroll
  for(int j=0;j<EDIM;j++){
    float ea = ep[j];
    v0 += ea * W1e_s[h0*EDIM + j];
    v1 += ea * W1e_s[h0*EDIM + EDIM + j];
  }
  float t0 = lk(u0 + v0), t1 = lk(u1 + v1);
  float p = t0*attl_s[h0] + t1*attl_s[h0+1];
  p = wsum(p);
  return lk(p + rn);
}

__global__ __launch_bounds__(256) void k_gate_agg(
   const int* __restrict__ ei, const float* __restrict__ eattr,
   const float* __restrict__ gcW, const float* __restrict__ attl,
   const float* __restrict__ r, const float* __restrict__ u,
   const float* __restrict__ x2, const float* __restrict__ gbias,
   const int* __restrict__ off, const int* __restrict__ perm,
   float* __restrict__ hout)
{
  __shared__ float W1e_s[H*EDIM];
  __shared__ float attl_s[H];
  __shared__ float scr[4][64];
  int tid = threadIdx.x;
  for(int i=tid;i<H*EDIM;i+=256) W1e_s[i] = gcW[(i/EDIM)*(H+EDIM) + H + (i%EDIM)];
  for(int i=tid;i<H;i+=256) attl_s[i] = attl[i];
  __syncthreads();
  int wave = tid >> 6, lane = tid & 63;
  int n = blockIdx.x*4 + wave;
  if (n >= NND) return;
  int o0 = off[n], deg = off[n+1] - o0;
  int h0 = lane*2;
  float rn = r[n];
  float mx = -3.4e38f;
  for(int i=0;i<deg;i++){
    float araw = gate_araw(perm[o0+i], h0, ei, eattr, u, W1e_s, attl_s, rn);
    if (lane == 0 && i < 64) scr[wave][i] = araw;
    mx = fmaxf(mx, araw);
  }
  float ss = 0.f;
  for(int i=0;i<deg;i++){
    float araw = (i < 64) ? scr[wave][i] : gate_araw(perm[o0+i], h0, ei, eattr, u, W1e_s, attl_s, rn);
    ss += __expf(araw - mx);
  }
  float inv = 1.f/(ss + 1e-16f);
  float a0 = 0.f, a1 = 0.f;
  for(int i=0;i<deg;i++){
    int e = perm[o0+i];
    float araw = (i < 64) ? scr[wave][i] : gate_araw(e, h0, ei, eattr, u, W1e_s, attl_s, rn);
    float w = __expf(araw - mx) * inv;
    int s = ei[e];
    a0 += w * x2[(size_t)s*H + h0];
    a1 += w * x2[(size_t)s*H + h0 + 1];
  }
  hout[(size_t)n*H + h0]     = eluf(a0 + gbias[h0]);
  hout[(size_t)n*H + h0 + 1] = eluf(a1 + gbias[h0+1]);
}

// ---------------- atom GATConv aggregation (wave per dst node) ----------------
__global__ __launch_bounds__(256) void k_atom_agg(
    const int* __restrict__ ei, const float* __restrict__ s1, const float* __restrict__ s2,
    const float* __restrict__ xl, const float* __restrict__ abias,
    const int* __restrict__ off, const int* __restrict__ perm,
    float* __restrict__ hout)
{
  __shared__ float scr[4][64];
  int tid = threadIdx.x, wave = tid >> 6, lane = tid & 63;
  int n = blockIdx.x*4 + wave;
  if (n >= NND) return;
  int o0 = off[n], deg = off[n+1] - o0;
  float s2n = s2[n];
  float mx = -3.4e38f;
  for(int i=0;i<deg;i++){
    float araw = lk(s1[ei[perm[o0+i]]] + s2n);
    if (lane == 0 && i < 64) scr[wave][i] = araw;
    mx = fmaxf(mx, araw);
  }
  float ss = 0.f;
  for(int i=0;i<deg;i++){
    float araw = (i < 64) ? scr[wave][i] : lk(s1[ei[perm[o0+i]]] + s2n);
    ss += __expf(araw - mx);
  }
  float inv = 1.f/(ss + 1e-16f);
  int h0 = lane*2;
  float a0 = 0.f, a1 = 0.f;
  for(int i=0;i<deg;i++){
    int e = perm[o0+i];
    float araw = (i < 64) ? scr[wave][i] : lk(s1[ei[e]] + s2n);
    float w = __expf(araw - mx) * inv;
    int s = ei[e];
    a0 += w * xl[(size_t)s*H + h0];
    a1 += w * xl[(size_t)s*H + h0 + 1];
  }
  hout[(size_t)n*H + h0]     = eluf(a0 + abias[h0]);
  hout[(size_t)n*H + h0 + 1] = eluf(a1 + abias[h0+1]);
}

// ---------------- graph readout: out0 = relu(segment_sum(xh)) ----------------
__global__ __launch_bounds__(256) void k_seg0(const float* __restrict__ xh, const int* __restrict__ goff,
                                              float* __restrict__ outg)
{
  int g = blockIdx.x*4 + (threadIdx.x >> 6);
  if (g >= NG) return;
  int lane = threadIdx.x & 63;
  int gs = goff[g], ge = goff[g+1];
  int h0 = lane*2;
  float a0 = 0.f, a1 = 0.f;
  for(int n=gs;n<ge;n++){
    const float* p = xh + (size_t)n*H + h0;
    a0 += p[0]; a1 += p[1];
  }
  outg[(size_t)g*H + h0]   = fmaxf(a0, 0.f);
  outg[(size_t)g*H + h0+1] = fmaxf(a1, 0.f);
}

// ---------------- molecule attention aggregation (wave per graph) ----------------
__global__ __launch_bounds__(256) void k_mol_agg(const float* __restrict__ asrc, const float* __restrict__ d,
    const float* __restrict__ xm, const int* __restrict__ goff,
    const float* __restrict__ mbias, float* __restrict__ hmol)
{
  int g = blockIdx.x*4 + (threadIdx.x >> 6);
  if (g >= NG) return;
  int lane = threadIdx.x & 63;
  int gs = goff[g], ge = goff[g+1];
  float dg = d[g];
  float mx = -3.4e38f;
  for(int i=gs+lane;i<ge;i+=64) mx = fmaxf(mx, lk(asrc[i] + dg));
  mx = wmax(mx);
  float ss = 0.f;
  for(int i=gs+lane;i<ge;i+=64) ss += __expf(lk(asrc[i] + dg) - mx);
  ss = wsum(ss);
  float inv = 1.f/(ss + 1e-16f);
  int h0 = lane*2;
  float a0 = 0.f, a1 = 0.f;
  for(int n=gs;n<ge;n++){
    float w = __expf(lk(asrc[n] + dg) - mx) * inv;
    a0 += w * xm[(size_t)n*H + h0];
    a1 += w * xm[(size_t)n*H + h0 + 1];
  }
  hmol[(size_t)g*H + h0]     = eluf(a0 + mbias[h0]);
  hmol[(size_t)g*H + h0 + 1] = eluf(a1 + mbias[h0+1]);
}

// ---------------- classifier head (wave per graph) -> FP32 output ----------------
__global__ __launch_bounds__(256) void k_cls(const float* __restrict__ emb,
   const float* __restrict__ W1, const float* __restrict__ b1,
   const float* __restrict__ W2, const float* __restrict__ b2,
   float* __restrict__ outp)
{
  __shared__ float W1t[H*64];   // [h][l]
  int tid = threadIdx.x;
  for(int i=tid;i<64*H;i+=256){
    int l = i >> 7, hh = i & 127;
    W1t[hh*64 + l] = W1[i];
  }
  __syncthreads();
  int wave = tid >> 6, lane = tid & 63;
  int g = blockIdx.x*4 + wave;
  if (g >= NG) return;
  const float* er = emb + (size_t)g*H;
  float acc = 0.f;
  for(int hh=0;hh<H;hh++) acc += er[hh] * W1t[hh*64 + lane];
  float hid = fmaxf(acc + b1[lane], 0.f);
  float p = hid * W2[lane];
  p = wsum(p);
  if (lane == 0) outp[g] = p + b2[0];
}

// =====================================================================================
extern "C" void kernel_launch(void* const* d_in, const int* in_sizes, int n_in,
                              void* d_out, int out_size, void* d_ws, size_t ws_size,
                              hipStream_t stream)
{
  const float* x      = (const float*)d_in[0];
  const float* eattr  = (const float*)d_in[1];
  const float* lin1W  = (const float*)d_in[2];
  const float* lin1b  = (const float*)d_in[3];
  const float* gcW    = (const float*)d_in[4];
  const float* gcatl  = (const float*)d_in[5];
  const float* gcatr  = (const float*)d_in[6];
  const float* gcW2   = (const float*)d_in[7];
  const float* gcb    = (const float*)d_in[8];
  const float* g0Wi   = (const float*)d_in[9];
  const float* g0Wh   = (const float*)d_in[10];
  const float* g0bi   = (const float*)d_in[11];
  const float* g0bh   = (const float*)d_in[12];
  const float* aW     = (const float*)d_in[13];
  const float* aas    = (const float*)d_in[14];
  const float* aad    = (const float*)d_in[15];
  const float* ab     = (const float*)d_in[16];
  const float* agWi   = (const float*)d_in[17];
  const float* agWh   = (const float*)d_in[18];
  const float* agbi   = (const float*)d_in[19];
  const float* agbh   = (const float*)d_in[20];
  const float* mW     = (const float*)d_in[21];
  const float* mas    = (const float*)d_in[22];
  const float* mad    = (const float*)d_in[23];
  const float* mb     = (const float*)d_in[24];
  const float* mgWi   = (const float*)d_in[25];
  const float* mgWh   = (const float*)d_in[26];
  const float* mgbi   = (const float*)d_in[27];
  const float* mgbh   = (const float*)d_in[28];
  const float* l2W    = (const float*)d_in[29];
  const float* l2b    = (const float*)d_in[30];
  const float* cW1    = (const float*)d_in[31];
  const float* cb1    = (const float*)d_in[32];
  const float* cW2    = (const float*)d_in[33];
  const float* cb2    = (const float*)d_in[34];
  const int* ei    = (const int*)d_in[35];
  const int* batch = (const int*)d_in[36];
  float* outp = (float*)d_out;

  char* p = (char*)d_ws;
  auto alloc = [&](size_t sz)->void*{ void* q = (void*)p; p += (sz + 511) & ~(size_t)511; return q; };
  float* x0            = (float*)alloc((size_t)NND*H*4);
  float* bu            = (float*)alloc((size_t)NND*H*4);
  float* bx2           = (float*)alloc((size_t)NND*H*4);
  float* bh            = (float*)alloc((size_t)NND*H*4);
  float* xh            = bx2;   // alias: bx2 dead after k_gate_agg
  float* xm            = x0;    // alias: x0 dead after first k_vgru
  float* rbuf          = (float*)alloc((size_t)NND*4);
  float* s1            = (float*)alloc((size_t)NND*4);
  float* s2            = (float*)alloc((size_t)NND*4);
  float* asrc          = (float*)alloc((size_t)NND*4);
  int* deg             = (int*)alloc((size_t)NND*4);
  int* off             = (int*)alloc((size_t)(NND+1)*4);
  int* cursor          = (int*)alloc((size_t)NND*4);
  int* perm            = (int*)alloc((size_t)NED*4);
  int* bsum            = (int*)alloc((size_t)(NBS+1)*4);
  int* goff            = (int*)alloc((size_t)(NG+1)*4);
  float* outg          = (float*)alloc((size_t)NG*H*4);
  float* hmol          = (float*)alloc((size_t)NG*H*4);
  float* om            = (float*)alloc((size_t)NG*H*4);
  float* emb           = (float*)alloc((size_t)NG*H*4);
  float* dg            = (float*)alloc((size_t)NG*4);

  // CSR by dst + graph offsets
  hipMemsetAsync(deg, 0, (size_t)NND*4, stream);
  k_hist<<<1563,256,0,stream>>>(ei, deg);
  k_scan1<<<NBS,256,0,stream>>>(deg, off, bsum);
  k_scan2<<<1,512,0,stream>>>(bsum);
  k_scan3<<<NBS,256,0,stream>>>(off, bsum, cursor);
  k_scatter<<<1563,256,0,stream>>>(ei, cursor, perm);
  k_gstart<<<NBS,256,0,stream>>>(batch, goff);

  // lin1 + leaky -> x0 fp32   (K=143)
  k_vgemm<true,1><<<25000,256,0,stream>>>(x, FEAT, FEAT, lin1W, FEAT, lin1b, x0, NND);

  // GATEConv
  k_rowdot<false><<<25000,256,0,stream>>>(x0, gcatr, nullptr, rbuf, nullptr, NND);
  k_vgemm<false,0><<<25000,256,0,stream>>>(x0, H, H, gcW, H+EDIM, nullptr, bu, NND);
  k_vgemm<false,0><<<25000,256,0,stream>>>(x0, H, H, gcW2, H, nullptr, bx2, NND);
  k_gate_agg<<<25000,256,0,stream>>>(ei, eattr, gcW, gcatl, rbuf, bu, bx2, gcb, off, perm, bh);
  k_vgru<<<25000,256,0,stream>>>(bh, x0, xh, g0Wi, g0Wh, g0bi, g0bh, NND);

  // atom GAT layers
  for(int l=0;l<2;l++){
    k_vgemm<false,0><<<25000,256,0,stream>>>(xh, H, H, aW + (size_t)l*H*H, H, nullptr, bu, NND);
    k_rowdot<true><<<25000,256,0,stream>>>(bu, aas + l*H, aad + l*H, s1, s2, NND);
    k_atom_agg<<<25000,256,0,stream>>>(ei, s1, s2, bu, ab + l*H, off, perm, bh);
    k_vgru<<<25000,256,0,stream>>>(bh, xh, xh, agWi + (size_t)l*3*H*H, agWh + (size_t)l*3*H*H,
                                   agbi + l*3*H, agbh + l*3*H, NND);
  }

  // molecule readout
  k_seg0<<<NG/4,256,0,stream>>>(xh, goff, outg);
  k_vgemm<false,0><<<25000,256,0,stream>>>(xh, H, H, mW, H, nullptr, xm, NND);
  k_rowdot<false><<<25000,256,0,stream>>>(xm, mas, nullptr, asrc, nullptr, NND);
  for(int t=0;t<2;t++){
    k_vgemm<false,0><<<NG/4,256,0,stream>>>(outg, H, H, mW, H, nullptr, om, NG);
    k_rowdot<false><<<NG/4,256,0,stream>>>(om, mad, nullptr, dg, nullptr, NG);
    k_mol_agg<<<NG/4,256,0,stream>>>(asrc, dg, xm, goff, mb, hmol);
    k_vgru<<<NG/4,256,0,stream>>>(hmol, outg, outg, mgWi, mgWh, mgbi, mgbh, NG);
  }

  // head
  k_vgemm<true,0><<<NG/4,256,0,stream>>>(outg, H, H, l2W, H, l2b, emb, NG);
  k_cls<<<NG/4,256,0,stream>>>(emb, cW1, cb1, cW2, cb2, outp);
}

// Round 5
// 1682.564 us; speedup vs baseline: 11.9537x; 11.9537x over previous
//
#include <hip/hip_runtime.h>

#define NND 100000   // nodes
#define NED 400000   // edges
#define FEAT 143
#define FEATP 160
#define EDIM 6
#define H 128
#define NG 4096      // graphs
#define NBS 391      // ceil(NND/256)

typedef __attribute__((ext_vector_type(8))) short bf8;
typedef __attribute__((ext_vector_type(4))) float f4;

__device__ __forceinline__ unsigned short f2b(float f){
  unsigned int u = __builtin_bit_cast(unsigned int, f);
  u = u + 0x7fffu + ((u >> 16) & 1u);   // RNE
  return (unsigned short)(u >> 16);
}
__device__ __forceinline__ float lk(float v){ return v >= 0.f ? v : 0.01f*v; }
__device__ __forceinline__ float eluf(float v){ return v > 0.f ? v : __expf(v) - 1.f; }
__device__ __forceinline__ float sgm(float v){ return 1.f/(1.f + __expf(-v)); }
__device__ __forceinline__ float wsum(float v){
  #pragma unroll
  for(int o=32;o>0;o>>=1) v += __shfl_xor(v,o);
  return v;
}
__device__ __forceinline__ float wmax(float v){
  #pragma unroll
  for(int o=32;o>0;o>>=1) v = fmaxf(v, __shfl_xor(v,o));
  return v;
}
// 16B-aligned fp32x8 -> bf16x8
__device__ __forceinline__ bf8 cvt8(const float* p){
  f4 a = *(const f4*)p;
  f4 b = *(const f4*)(p+4);
  bf8 t;
  t[0]=(short)f2b(a[0]); t[1]=(short)f2b(a[1]); t[2]=(short)f2b(a[2]); t[3]=(short)f2b(a[3]);
  t[4]=(short)f2b(b[0]); t[5]=(short)f2b(b[1]); t[6]=(short)f2b(b[2]); t[7]=(short)f2b(b[3]);
  return t;
}

// ---------------- weight fp32 -> bf16 conversion ----------------
__global__ __launch_bounds__(256) void k_cvtw(const float* __restrict__ src, unsigned short* __restrict__ dst, int n){
  int i = blockIdx.x*256 + threadIdx.x;
  if (i < n) dst[i] = f2b(src[i]);
}
// strided: dst[r*ldd+c] = src[r*lds+c], total = rows*ldd
__global__ __launch_bounds__(256) void k_cvtw2(const float* __restrict__ src, int lds,
                                               unsigned short* __restrict__ dst, int ldd, int total){
  int i = blockIdx.x*256 + threadIdx.x;
  if (i < total){
    int r = i/ldd, c = i - r*ldd;
    dst[i] = f2b(src[(size_t)r*lds + c]);
  }
}

// ---------------- CSR build (counting sort of edges by dst) ----------------
__global__ __launch_bounds__(256) void k_hist(const int* __restrict__ ei, int* __restrict__ deg){
  int e = blockIdx.x*256 + threadIdx.x;
  if (e < NED) atomicAdd(&deg[ei[NED + e]], 1);
}
__global__ __launch_bounds__(256) void k_scan1(const int* __restrict__ deg, int* __restrict__ off, int* __restrict__ bsum){
  __shared__ int s[256];
  int i = blockIdx.x*256 + threadIdx.x;
  int v = (i < NND) ? deg[i] : 0;
  s[threadIdx.x] = v; __syncthreads();
  for(int o=1;o<256;o<<=1){
    int t = 0; if (threadIdx.x >= o) t = s[threadIdx.x - o];
    __syncthreads(); s[threadIdx.x] += t; __syncthreads();
  }
  if (i < NND) off[i] = s[threadIdx.x] - v;
  if (threadIdx.x == 255) bsum[blockIdx.x] = s[255];
}
__global__ __launch_bounds__(512) void k_scan2(int* __restrict__ bsum){
  __shared__ int s[512];
  int t = threadIdx.x;
  int v = (t < NBS) ? bsum[t] : 0;
  s[t] = v; __syncthreads();
  for(int o=1;o<512;o<<=1){
    int x = 0; if (t >= o) x = s[t - o];
    __syncthreads(); s[t] += x; __syncthreads();
  }
  if (t < NBS) bsum[t] = s[t] - v;
  if (t == 511) bsum[NBS] = s[511];
}
__global__ __launch_bounds__(256) void k_scan3(int* __restrict__ off, const int* __restrict__ bsum, int* __restrict__ cursor){
  int i = blockIdx.x*256 + threadIdx.x;
  if (i < NND){
    int v = off[i] + bsum[blockIdx.x];
    off[i] = v; cursor[i] = v;
  }
  if (i == 0) off[NND] = bsum[NBS];
}
__global__ __launch_bounds__(256) void k_scatter(const int* __restrict__ ei, int* __restrict__ cursor, int* __restrict__ perm){
  int e = blockIdx.x*256 + threadIdx.x;
  if (e < NED){
    int p = atomicAdd(&cursor[ei[NED + e]], 1);
    perm[p] = e;
  }
}
__global__ __launch_bounds__(256) void k_gstart(const int* __restrict__ batch, int* __restrict__ goff){
  int i = blockIdx.x*256 + threadIdx.x;
  if (i >= NND) return;
  int bi = batch[i];
  int bp = (i > 0) ? batch[i-1] : -1;
  for(int g = bp+1; g <= bi; g++) goff[g] = i;
  if (i == NND-1) for(int g = bi+1; g <= NG; g++) goff[g] = NND;
}

// ---------------- pad + fp32->bf16 for lin1 (K=143 -> 160) ----------------
__global__ __launch_bounds__(256) void k_padx(const float* __restrict__ x, unsigned short* __restrict__ xp){
  int r = blockIdx.x*4 + (threadIdx.x >> 6);
  int lane = threadIdx.x & 63;
  if (r >= NND) return;
  for(int i = lane; i < FEATP; i += 64)
    xp[(size_t)r*FEATP + i] = (i < FEAT) ? f2b(x[(size_t)r*FEAT + i]) : (unsigned short)0;
}
__global__ __launch_bounds__(256) void k_padw(const float* __restrict__ w, unsigned short* __restrict__ wp){
  int r = blockIdx.x*4 + (threadIdx.x >> 6);
  int lane = threadIdx.x & 63;
  if (r >= H) return;
  for(int i = lane; i < FEATP; i += 64)
    wp[(size_t)r*FEATP + i] = (i < FEAT) ? f2b(w[(size_t)r*FEAT + i]) : (unsigned short)0;
}

// ---------------- MFMA GEMM: C[M,128] = act(A[M,K] @ Wb[:,:K]^T + bias), C fp32 ----------------
// grid.x = M/16, block 256 = 4 waves; wave computes 16 rows x 32 cols.
// A fragment: A[m=lane&15][k=quad*8+j]; B fragment: W[n=lane&15][k=quad*8+j]; C: col=lane&15,row=quad*4+i.
template<int KB, bool ABF16, bool BIAS, int ACT>
__global__ __launch_bounds__(256) void k_gemm(const void* __restrict__ Ap, int lda,
        const unsigned short* __restrict__ Wp, int ldw,
        const float* __restrict__ bias, float* __restrict__ C)
{
  int tid = threadIdx.x, wave = tid >> 6, lane = tid & 63;
  int m = lane & 15, quad = lane >> 4;
  int r0 = blockIdx.x * 16;
  bf8 a[KB];
  if (ABF16){
    const unsigned short* base = (const unsigned short*)Ap + (size_t)(r0+m)*lda + quad*8;
    #pragma unroll
    for(int kb=0;kb<KB;kb++) a[kb] = *(const bf8*)(base + kb*32);
  } else {
    const float* base = (const float*)Ap + (size_t)(r0+m)*lda + quad*8;
    #pragma unroll
    for(int kb=0;kb<KB;kb++) a[kb] = cvt8(base + kb*32);
  }
  int c0 = wave * 32;
  #pragma unroll
  for(int ct=0;ct<2;ct++){
    int n = c0 + ct*16 + m;
    const unsigned short* wb = Wp + (size_t)n*ldw + quad*8;
    f4 acc = {0.f,0.f,0.f,0.f};
    #pragma unroll
    for(int kb=0;kb<KB;kb++){
      bf8 b = *(const bf8*)(wb + kb*32);
      acc = __builtin_amdgcn_mfma_f32_16x16x32_bf16(a[kb], b, acc, 0, 0, 0);
    }
    float bv = BIAS ? bias[n] : 0.f;
    #pragma unroll
    for(int i=0;i<4;i++){
      int row = r0 + quad*4 + i;
      float v = acc[i] + bv;
      if (ACT == 1) v = lk(v);
      C[(size_t)row*H + n] = v;
    }
  }
}

// ---------------- fused MFMA GRU: Out = relu(gru(Xin, Hid)), 16 rows/block ----------------
// Xin/Hid/Out fp32 [*,H]; Wi/Wh bf16 [3H,H]; bi/bh fp32 [3H]. Out may alias Hid (row-local RMW).
__global__ __launch_bounds__(256) void k_gru(const float* __restrict__ Xin,
      const float* __restrict__ Hid, float* __restrict__ Out,
      const unsigned short* __restrict__ Wi, const unsigned short* __restrict__ Wh,
      const float* __restrict__ bi, const float* __restrict__ bh)
{
  __shared__ float gi[16*385];
  __shared__ float gh[16*385];
  int tid = threadIdx.x, wave = tid >> 6, lane = tid & 63;
  int m = lane & 15, quad = lane >> 4;
  int r0 = blockIdx.x * 16;
  bf8 ax[4], ah[4];
  const float* xb = Xin + (size_t)(r0+m)*H + quad*8;
  const float* hb = Hid + (size_t)(r0+m)*H + quad*8;
  #pragma unroll
  for(int kb=0;kb<4;kb++){
    ax[kb] = cvt8(xb + kb*32);
    ah[kb] = cvt8(hb + kb*32);
  }
  #pragma unroll
  for(int ct=0;ct<6;ct++){
    int n = wave*96 + ct*16 + m;   // 0..383
    const unsigned short* wib = Wi + (size_t)n*H + quad*8;
    const unsigned short* whb = Wh + (size_t)n*H + quad*8;
    f4 ai = {0.f,0.f,0.f,0.f}, ahh = {0.f,0.f,0.f,0.f};
    #pragma unroll
    for(int kb=0;kb<4;kb++){
      bf8 wbi = *(const bf8*)(wib + kb*32);
      bf8 wbh = *(const bf8*)(whb + kb*32);
      ai  = __builtin_amdgcn_mfma_f32_16x16x32_bf16(ax[kb], wbi, ai, 0,0,0);
      ahh = __builtin_amdgcn_mfma_f32_16x16x32_bf16(ah[kb], wbh, ahh, 0,0,0);
    }
    #pragma unroll
    for(int i=0;i<4;i++){
      gi[(quad*4+i)*385 + n] = ai[i];
      gh[(quad*4+i)*385 + n] = ahh[i];
    }
  }
  __syncthreads();
  #pragma unroll
  for(int it=0; it<8; it++){
    int idx = tid + it*256;          // 0..2047
    int row = idx >> 7, col = idx & 127;
    float gir = gi[row*385+col]     + bi[col];
    float giz = gi[row*385+col+128] + bi[col+128];
    float gin = gi[row*385+col+256] + bi[col+256];
    float ghr = gh[row*385+col]     + bh[col];
    float ghz = gh[row*385+col+128] + bh[col+128];
    float ghn = gh[row*385+col+256] + bh[col+256];
    float hv  = Hid[(size_t)(r0+row)*H + col];
    float rg = sgm(gir + ghr);
    float zg = sgm(giz + ghz);
    float ng = tanhf(gin + rg*ghn);
    float o = (1.f - zg)*ng + zg*hv;
    Out[(size_t)(r0+row)*H + col] = fmaxf(o, 0.f);
  }
}

// ---------------- row dot products: o[n] = A[n,:] . v  (all fp32) ----------------
template<bool TWO>
__global__ __launch_bounds__(256) void k_rowdot(const float* __restrict__ A,
    const float* __restrict__ v1, const float* __restrict__ v2,
    float* __restrict__ o1, float* __restrict__ o2, int M)
{
  int idx = blockIdx.x*4 + (threadIdx.x >> 6);
  if (idx >= M) return;
  int lane = threadIdx.x & 63;
  int h0 = lane*2;
  float a0 = A[(size_t)idx*H + h0];
  float a1 = A[(size_t)idx*H + h0 + 1];
  float p1 = a0*v1[h0] + a1*v1[h0+1];
  p1 = wsum(p1);
  if (lane == 0) o1[idx] = p1;
  if (TWO){
    float p2 = a0*v2[h0] + a1*v2[h0+1];
    p2 = wsum(p2);
    if (lane == 0) o2[idx] = p2;
  }
}

// ---------------- GATEConv edge attention + aggregation (wave per dst node) ----------------
__device__ __forceinline__ float gate_araw(int e, int h0,
    const int* __restrict__ ei, const float* __restrict__ eattr,
    const float* __restrict__ u, const float* W1e_s, const float* attl_s, float rn)
{
  int s = ei[e];
  float u0 = u[(size_t)s*H + h0];
  float u1 = u[(size_t)s*H + h0 + 1];
  const float* ep = eattr + (size_t)e*EDIM;
  float v0 = 0.f, v1 = 0.f;
  #pragma unroll
  for(int j=0;j<EDIM;j++){
    float ea = ep[j];
    v0 += ea * W1e_s[h0*EDIM + j];
    v1 += ea * W1e_s[h0*EDIM + EDIM + j];
  }
  float t0 = lk(u0 + v0), t1 = lk(u1 + v1);
  float p = t0*attl_s[h0] + t1*attl_s[h0+1];
  p = wsum(p);
  return lk(p + rn);
}

__global__ __launch_bounds__(256) void k_gate_agg(
   const int* __restrict__ ei, const float* __restrict__ eattr,
   const float* __restrict__ gcW, const float* __restrict__ attl,
   const float* __restrict__ r, const float* __restrict__ u,
   const float* __restrict__ x2, const float* __restrict__ gbias,
   const int* __restrict__ off, const int* __restrict__ perm,
   float* __restrict__ hout)
{
  __shared__ float W1e_s[H*EDIM];
  __shared__ float attl_s[H];
  __shared__ float scr[4][64];
  int tid = threadIdx.x;
  for(int i=tid;i<H*EDIM;i+=256) W1e_s[i] = gcW[(i/EDIM)*(H+EDIM) + H + (i%EDIM)];
  for(int i=tid;i<H;i+=256) attl_s[i] = attl[i];
  __syncthreads();
  int wave = tid >> 6, lane = tid & 63;
  int n = blockIdx.x*4 + wave;
  if (n >= NND) return;
  int o0 = off[n], deg = off[n+1] - o0;
  int h0 = lane*2;
  float rn = r[n];
  float mx = -3.4e38f;
  for(int i=0;i<deg;i++){
    float araw = gate_araw(perm[o0+i], h0, ei, eattr, u, W1e_s, attl_s, rn);
    if (lane == 0 && i < 64) scr[wave][i] = araw;
    mx = fmaxf(mx, araw);
  }
  float ss = 0.f;
  for(int i=0;i<deg;i++){
    float araw = (i < 64) ? scr[wave][i] : gate_araw(perm[o0+i], h0, ei, eattr, u, W1e_s, attl_s, rn);
    ss += __expf(araw - mx);
  }
  float inv = 1.f/(ss + 1e-16f);
  float a0 = 0.f, a1 = 0.f;
  for(int i=0;i<deg;i++){
    int e = perm[o0+i];
    float araw = (i < 64) ? scr[wave][i] : gate_araw(e, h0, ei, eattr, u, W1e_s, attl_s, rn);
    float w = __expf(araw - mx) * inv;
    int s = ei[e];
    a0 += w * x2[(size_t)s*H + h0];
    a1 += w * x2[(size_t)s*H + h0 + 1];
  }
  hout[(size_t)n*H + h0]     = eluf(a0 + gbias[h0]);
  hout[(size_t)n*H + h0 + 1] = eluf(a1 + gbias[h0+1]);
}

// ---------------- atom GATConv aggregation (wave per dst node) ----------------
__global__ __launch_bounds__(256) void k_atom_agg(
    const int* __restrict__ ei, const float* __restrict__ s1, const float* __restrict__ s2,
    const float* __restrict__ xl, const float* __restrict__ abias,
    const int* __restrict__ off, const int* __restrict__ perm,
    float* __restrict__ hout)
{
  __shared__ float scr[4][64];
  int tid = threadIdx.x, wave = tid >> 6, lane = tid & 63;
  int n = blockIdx.x*4 + wave;
  if (n >= NND) return;
  int o0 = off[n], deg = off[n+1] - o0;
  float s2n = s2[n];
  float mx = -3.4e38f;
  for(int i=0;i<deg;i++){
    float araw = lk(s1[ei[perm[o0+i]]] + s2n);
    if (lane == 0 && i < 64) scr[wave][i] = araw;
    mx = fmaxf(mx, araw);
  }
  float ss = 0.f;
  for(int i=0;i<deg;i++){
    float araw = (i < 64) ? scr[wave][i] : lk(s1[ei[perm[o0+i]]] + s2n);
    ss += __expf(araw - mx);
  }
  float inv = 1.f/(ss + 1e-16f);
  int h0 = lane*2;
  float a0 = 0.f, a1 = 0.f;
  for(int i=0;i<deg;i++){
    int e = perm[o0+i];
    float araw = (i < 64) ? scr[wave][i] : lk(s1[ei[e]] + s2n);
    float w = __expf(araw - mx) * inv;
    int s = ei[e];
    a0 += w * xl[(size_t)s*H + h0];
    a1 += w * xl[(size_t)s*H + h0 + 1];
  }
  hout[(size_t)n*H + h0]     = eluf(a0 + abias[h0]);
  hout[(size_t)n*H + h0 + 1] = eluf(a1 + abias[h0+1]);
}

// ---------------- graph readout: out0 = relu(segment_sum(xh)) ----------------
__global__ __launch_bounds__(256) void k_seg0(const float* __restrict__ xh, const int* __restrict__ goff,
                                              float* __restrict__ outg)
{
  int g = blockIdx.x*4 + (threadIdx.x >> 6);
  if (g >= NG) return;
  int lane = threadIdx.x & 63;
  int gs = goff[g], ge = goff[g+1];
  int h0 = lane*2;
  float a0 = 0.f, a1 = 0.f;
  for(int n=gs;n<ge;n++){
    const float* p = xh + (size_t)n*H + h0;
    a0 += p[0]; a1 += p[1];
  }
  outg[(size_t)g*H + h0]   = fmaxf(a0, 0.f);
  outg[(size_t)g*H + h0+1] = fmaxf(a1, 0.f);
}

// ---------------- molecule attention aggregation (wave per graph) ----------------
__global__ __launch_bounds__(256) void k_mol_agg(const float* __restrict__ asrc, const float* __restrict__ d,
    const float* __restrict__ xm, const int* __restrict__ goff,
    const float* __restrict__ mbias, float* __restrict__ hmol)
{
  int g = blockIdx.x*4 + (threadIdx.x >> 6);
  if (g >= NG) return;
  int lane = threadIdx.x & 63;
  int gs = goff[g], ge = goff[g+1];
  float dg = d[g];
  float mx = -3.4e38f;
  for(int i=gs+lane;i<ge;i+=64) mx = fmaxf(mx, lk(asrc[i] + dg));
  mx = wmax(mx);
  float ss = 0.f;
  for(int i=gs+lane;i<ge;i+=64) ss += __expf(lk(asrc[i] + dg) - mx);
  ss = wsum(ss);
  float inv = 1.f/(ss + 1e-16f);
  int h0 = lane*2;
  float a0 = 0.f, a1 = 0.f;
  for(int n=gs;n<ge;n++){
    float w = __expf(lk(asrc[n] + dg) - mx) * inv;
    a0 += w * xm[(size_t)n*H + h0];
    a1 += w * xm[(size_t)n*H + h0 + 1];
  }
  hmol[(size_t)g*H + h0]     = eluf(a0 + mbias[h0]);
  hmol[(size_t)g*H + h0 + 1] = eluf(a1 + mbias[h0+1]);
}

// ---------------- classifier head (wave per graph) -> FP32 output ----------------
__global__ __launch_bounds__(256) void k_cls(const float* __restrict__ emb,
   const float* __restrict__ W1, const float* __restrict__ b1,
   const float* __restrict__ W2, const float* __restrict__ b2,
   float* __restrict__ outp)
{
  __shared__ float W1t[H*64];   // [h][l]
  int tid = threadIdx.x;
  for(int i=tid;i<64*H;i+=256){
    int l = i >> 7, hh = i & 127;
    W1t[hh*64 + l] = W1[i];
  }
  __syncthreads();
  int wave = tid >> 6, lane = tid & 63;
  int g = blockIdx.x*4 + wave;
  if (g >= NG) return;
  const float* er = emb + (size_t)g*H;
  float acc = 0.f;
  for(int hh=0;hh<H;hh++) acc += er[hh] * W1t[hh*64 + lane];
  float hid = fmaxf(acc + b1[lane], 0.f);
  float p = hid * W2[lane];
  p = wsum(p);
  if (lane == 0) outp[g] = p + b2[0];
}

// =====================================================================================
extern "C" void kernel_launch(void* const* d_in, const int* in_sizes, int n_in,
                              void* d_out, int out_size, void* d_ws, size_t ws_size,
                              hipStream_t stream)
{
  const float* x      = (const float*)d_in[0];
  const float* eattr  = (const float*)d_in[1];
  const float* lin1W  = (const float*)d_in[2];
  const float* lin1b  = (const float*)d_in[3];
  const float* gcW    = (const float*)d_in[4];
  const float* gcatl  = (const float*)d_in[5];
  const float* gcatr  = (const float*)d_in[6];
  const float* gcW2   = (const float*)d_in[7];
  const float* gcb    = (const float*)d_in[8];
  const float* g0Wi   = (const float*)d_in[9];
  const float* g0Wh   = (const float*)d_in[10];
  const float* g0bi   = (const float*)d_in[11];
  const float* g0bh   = (const float*)d_in[12];
  const float* aW     = (const float*)d_in[13];
  const float* aas    = (const float*)d_in[14];
  const float* aad    = (const float*)d_in[15];
  const float* ab     = (const float*)d_in[16];
  const float* agWi   = (const float*)d_in[17];
  const float* agWh   = (const float*)d_in[18];
  const float* agbi   = (const float*)d_in[19];
  const float* agbh   = (const float*)d_in[20];
  const float* mW     = (const float*)d_in[21];
  const float* mas    = (const float*)d_in[22];
  const float* mad    = (const float*)d_in[23];
  const float* mb     = (const float*)d_in[24];
  const float* mgWi   = (const float*)d_in[25];
  const float* mgWh   = (const float*)d_in[26];
  const float* mgbi   = (const float*)d_in[27];
  const float* mgbh   = (const float*)d_in[28];
  const float* l2W    = (const float*)d_in[29];
  const float* l2b    = (const float*)d_in[30];
  const float* cW1    = (const float*)d_in[31];
  const float* cb1    = (const float*)d_in[32];
  const float* cW2    = (const float*)d_in[33];
  const float* cb2    = (const float*)d_in[34];
  const int* ei    = (const int*)d_in[35];
  const int* batch = (const int*)d_in[36];
  float* outp = (float*)d_out;

  char* p = (char*)d_ws;
  auto alloc = [&](size_t sz)->void*{ void* q = (void*)p; p += (sz + 511) & ~(size_t)511; return q; };
  float* x0            = (float*)alloc((size_t)NND*H*4);
  float* bu            = (float*)alloc((size_t)NND*H*4);
  float* bx2           = (float*)alloc((size_t)NND*H*4);
  float* bh            = (float*)alloc((size_t)NND*H*4);
  float* xh            = bx2;   // alias: bx2 dead after k_gate_agg
  float* xm            = x0;    // alias: x0 dead after first k_gru
  unsigned short* xp   = (unsigned short*)bh;  // alias: bh first written at k_gate_agg (after lin1 reads xp)
  float* rbuf          = (float*)alloc((size_t)NND*4);
  float* s1            = (float*)alloc((size_t)NND*4);
  float* s2            = (float*)alloc((size_t)NND*4);
  float* asrc          = (float*)alloc((size_t)NND*4);
  int* deg             = (int*)alloc((size_t)NND*4);
  int* off             = (int*)alloc((size_t)(NND+1)*4);
  int* cursor          = (int*)alloc((size_t)NND*4);
  int* perm            = (int*)alloc((size_t)NED*4);
  int* bsum            = (int*)alloc((size_t)(NBS+1)*4);
  int* goff            = (int*)alloc((size_t)(NG+1)*4);
  float* outg          = (float*)alloc((size_t)NG*H*4);
  float* hmol          = (float*)alloc((size_t)NG*H*4);
  float* om            = (float*)alloc((size_t)NG*H*4);
  float* emb           = (float*)alloc((size_t)NG*H*4);
  float* dg            = (float*)alloc((size_t)NG*4);
  // bf16 weight buffers (~1 MB)
  unsigned short* wp     = (unsigned short*)alloc((size_t)H*FEATP*2);
  unsigned short* gcWnb  = (unsigned short*)alloc((size_t)H*H*2);
  unsigned short* gcW2b  = (unsigned short*)alloc((size_t)H*H*2);
  unsigned short* g0Wib  = (unsigned short*)alloc((size_t)3*H*H*2);
  unsigned short* g0Whb  = (unsigned short*)alloc((size_t)3*H*H*2);
  unsigned short* aWb    = (unsigned short*)alloc((size_t)2*H*H*2);
  unsigned short* agWib  = (unsigned short*)alloc((size_t)2*3*H*H*2);
  unsigned short* agWhb  = (unsigned short*)alloc((size_t)2*3*H*H*2);
  unsigned short* mWb    = (unsigned short*)alloc((size_t)H*H*2);
  unsigned short* l2Wb   = (unsigned short*)alloc((size_t)H*H*2);
  unsigned short* mgWib  = (unsigned short*)alloc((size_t)3*H*H*2);
  unsigned short* mgWhb  = (unsigned short*)alloc((size_t)3*H*H*2);

  const int HH = H*H, H3H = 3*H*H;
  // weight conversions
  k_padw <<<32,256,0,stream>>>(lin1W, wp);
  k_cvtw2<<<(HH+255)/256,256,0,stream>>>(gcW, H+EDIM, gcWnb, H, HH);
  k_cvtw <<<(HH+255)/256,256,0,stream>>>(gcW2, gcW2b, HH);
  k_cvtw <<<(H3H+255)/256,256,0,stream>>>(g0Wi, g0Wib, H3H);
  k_cvtw <<<(H3H+255)/256,256,0,stream>>>(g0Wh, g0Whb, H3H);
  k_cvtw <<<(2*HH+255)/256,256,0,stream>>>(aW, aWb, 2*HH);
  k_cvtw <<<(2*H3H+255)/256,256,0,stream>>>(agWi, agWib, 2*H3H);
  k_cvtw <<<(2*H3H+255)/256,256,0,stream>>>(agWh, agWhb, 2*H3H);
  k_cvtw <<<(HH+255)/256,256,0,stream>>>(mW, mWb, HH);
  k_cvtw <<<(HH+255)/256,256,0,stream>>>(l2W, l2Wb, HH);
  k_cvtw <<<(H3H+255)/256,256,0,stream>>>(mgWi, mgWib, H3H);
  k_cvtw <<<(H3H+255)/256,256,0,stream>>>(mgWh, mgWhb, H3H);

  // CSR by dst + graph offsets
  hipMemsetAsync(deg, 0, (size_t)NND*4, stream);
  k_hist<<<1563,256,0,stream>>>(ei, deg);
  k_scan1<<<NBS,256,0,stream>>>(deg, off, bsum);
  k_scan2<<<1,512,0,stream>>>(bsum);
  k_scan3<<<NBS,256,0,stream>>>(off, bsum, cursor);
  k_scatter<<<1563,256,0,stream>>>(ei, cursor, perm);
  k_gstart<<<NBS,256,0,stream>>>(batch, goff);

  // lin1 + leaky -> x0 fp32  (padded K=160, bf16 A and W)
  k_padx<<<25000,256,0,stream>>>(x, xp);
  k_gemm<5,true,true,1><<<NND/16,256,0,stream>>>(xp, FEATP, wp, FEATP, lin1b, x0);

  // GATEConv
  k_rowdot<false><<<25000,256,0,stream>>>(x0, gcatr, nullptr, rbuf, nullptr, NND);
  k_gemm<4,false,false,0><<<NND/16,256,0,stream>>>(x0, H, gcWnb, H, nullptr, bu);
  k_gemm<4,false,false,0><<<NND/16,256,0,stream>>>(x0, H, gcW2b, H, nullptr, bx2);
  k_gate_agg<<<25000,256,0,stream>>>(ei, eattr, gcW, gcatl, rbuf, bu, bx2, gcb, off, perm, bh);
  k_gru<<<NND/16,256,0,stream>>>(bh, x0, xh, g0Wib, g0Whb, g0bi, g0bh);

  // atom GAT layers
  for(int l=0;l<2;l++){
    k_gemm<4,false,false,0><<<NND/16,256,0,stream>>>(xh, H, aWb + (size_t)l*HH, H, nullptr, bu);
    k_rowdot<true><<<25000,256,0,stream>>>(bu, aas + l*H, aad + l*H, s1, s2, NND);
    k_atom_agg<<<25000,256,0,stream>>>(ei, s1, s2, bu, ab + l*H, off, perm, bh);
    k_gru<<<NND/16,256,0,stream>>>(bh, xh, xh, agWib + (size_t)l*H3H, agWhb + (size_t)l*H3H,
                                   agbi + l*3*H, agbh + l*3*H);
  }

  // molecule readout
  k_seg0<<<NG/4,256,0,stream>>>(xh, goff, outg);
  k_gemm<4,false,false,0><<<NND/16,256,0,stream>>>(xh, H, mWb, H, nullptr, xm);
  k_rowdot<false><<<25000,256,0,stream>>>(xm, mas, nullptr, asrc, nullptr, NND);
  for(int t=0;t<2;t++){
    k_gemm<4,false,false,0><<<NG/16,256,0,stream>>>(outg, H, mWb, H, nullptr, om);
    k_rowdot<false><<<NG/4,256,0,stream>>>(om, mad, nullptr, dg, nullptr, NG);
    k_mol_agg<<<NG/4,256,0,stream>>>(asrc, dg, xm, goff, mb, hmol);
    k_gru<<<NG/16,256,0,stream>>>(hmol, outg, outg, mgWib, mgWhb, mgbi, mgbh);
  }

  // head
  k_gemm<4,false,true,0><<<NG/16,256,0,stream>>>(outg, H, l2Wb, H, l2b, emb);
  k_cls<<<NG/4,256,0,stream>>>(emb, cW1, cb1, cW2, cb2, outp);
}

// Round 6
// 1411.254 us; speedup vs baseline: 14.2518x; 1.1922x over previous
//
#include <hip/hip_runtime.h>

#define NND 100000   // nodes
#define NED 400000   // edges
#define FEAT 143
#define FEATP 160
#define EDIM 6
#define H 128
#define NG 4096      // graphs
#define NBS 391      // ceil(NND/256)

typedef __attribute__((ext_vector_type(8))) short bf8;
typedef __attribute__((ext_vector_type(4))) float f4;

__device__ __forceinline__ float b2f(unsigned short u){
  unsigned int x = ((unsigned int)u) << 16;
  return __builtin_bit_cast(float, x);
}
__device__ __forceinline__ unsigned short f2b(float f){
  unsigned int u = __builtin_bit_cast(unsigned int, f);
  u = u + 0x7fffu + ((u >> 16) & 1u);   // RNE
  return (unsigned short)(u >> 16);
}
__device__ __forceinline__ float lk(float v){ return v >= 0.f ? v : 0.01f*v; }
__device__ __forceinline__ float eluf(float v){ return v > 0.f ? v : __expf(v) - 1.f; }
__device__ __forceinline__ float sgm(float v){ return 1.f/(1.f + __expf(-v)); }
__device__ __forceinline__ float wsum(float v){
  #pragma unroll
  for(int o=32;o>0;o>>=1) v += __shfl_xor(v,o);
  return v;
}
// 16B-aligned fp32x8 -> bf16x8
__device__ __forceinline__ bf8 cvt8(const float* p){
  f4 a = *(const f4*)p;
  f4 b = *(const f4*)(p+4);
  bf8 t;
  t[0]=(short)f2b(a[0]); t[1]=(short)f2b(a[1]); t[2]=(short)f2b(a[2]); t[3]=(short)f2b(a[3]);
  t[4]=(short)f2b(b[0]); t[5]=(short)f2b(b[1]); t[6]=(short)f2b(b[2]); t[7]=(short)f2b(b[3]);
  return t;
}

// ---------------- weight fp32 -> bf16 ----------------
__global__ __launch_bounds__(256) void k_cvtw(const float* __restrict__ src, unsigned short* __restrict__ dst, int n){
  int i = blockIdx.x*256 + threadIdx.x;
  if (i < n) dst[i] = f2b(src[i]);
}
__global__ __launch_bounds__(256) void k_cvtw2(const float* __restrict__ src, int lds,
                                               unsigned short* __restrict__ dst, int ldd, int total){
  int i = blockIdx.x*256 + threadIdx.x;
  if (i < total){
    int r = i/ldd, c = i - r*ldd;
    dst[i] = f2b(src[(size_t)r*lds + c]);
  }
}

// ---------------- CSR build (counting sort of edges by dst) ----------------
__global__ __launch_bounds__(256) void k_hist(const int* __restrict__ ei, int* __restrict__ deg){
  int e = blockIdx.x*256 + threadIdx.x;
  if (e < NED) atomicAdd(&deg[ei[NED + e]], 1);
}
__global__ __launch_bounds__(256) void k_scan1(const int* __restrict__ deg, int* __restrict__ off, int* __restrict__ bsum){
  __shared__ int s[256];
  int i = blockIdx.x*256 + threadIdx.x;
  int v = (i < NND) ? deg[i] : 0;
  s[threadIdx.x] = v; __syncthreads();
  for(int o=1;o<256;o<<=1){
    int t = 0; if (threadIdx.x >= o) t = s[threadIdx.x - o];
    __syncthreads(); s[threadIdx.x] += t; __syncthreads();
  }
  if (i < NND) off[i] = s[threadIdx.x] - v;
  if (threadIdx.x == 255) bsum[blockIdx.x] = s[255];
}
__global__ __launch_bounds__(512) void k_scan2(int* __restrict__ bsum){
  __shared__ int s[512];
  int t = threadIdx.x;
  int v = (t < NBS) ? bsum[t] : 0;
  s[t] = v; __syncthreads();
  for(int o=1;o<512;o<<=1){
    int x = 0; if (t >= o) x = s[t - o];
    __syncthreads(); s[t] += x; __syncthreads();
  }
  if (t < NBS) bsum[t] = s[t] - v;
  if (t == 511) bsum[NBS] = s[511];
}
__global__ __launch_bounds__(256) void k_scan3(int* __restrict__ off, const int* __restrict__ bsum, int* __restrict__ cursor){
  int i = blockIdx.x*256 + threadIdx.x;
  if (i < NND){
    int v = off[i] + bsum[blockIdx.x];
    off[i] = v; cursor[i] = v;
  }
  if (i == 0) off[NND] = bsum[NBS];
}
__global__ __launch_bounds__(256) void k_scatter(const int* __restrict__ ei, int* __restrict__ cursor, int* __restrict__ perm){
  int e = blockIdx.x*256 + threadIdx.x;
  if (e < NED){
    int p = atomicAdd(&cursor[ei[NED + e]], 1);
    perm[p] = e;
  }
}
__global__ __launch_bounds__(256) void k_gstart(const int* __restrict__ batch, int* __restrict__ goff){
  int i = blockIdx.x*256 + threadIdx.x;
  if (i >= NND) return;
  int bi = batch[i];
  int bp = (i > 0) ? batch[i-1] : -1;
  for(int g = bp+1; g <= bi; g++) goff[g] = i;
  if (i == NND-1) for(int g = bi+1; g <= NG; g++) goff[g] = NND;
}

// ---------------- pad + fp32->bf16 for lin1 (K=143 -> 160) ----------------
__global__ __launch_bounds__(256) void k_padx(const float* __restrict__ x, unsigned short* __restrict__ xp){
  int r = blockIdx.x*4 + (threadIdx.x >> 6);
  int lane = threadIdx.x & 63;
  if (r >= NND) return;
  for(int i = lane; i < FEATP; i += 64)
    xp[(size_t)r*FEATP + i] = (i < FEAT) ? f2b(x[(size_t)r*FEAT + i]) : (unsigned short)0;
}
__global__ __launch_bounds__(256) void k_padw(const float* __restrict__ w, unsigned short* __restrict__ wp){
  int r = blockIdx.x*4 + (threadIdx.x >> 6);
  int lane = threadIdx.x & 63;
  if (r >= H) return;
  for(int i = lane; i < FEATP; i += 64)
    wp[(size_t)r*FEATP + i] = (i < FEAT) ? f2b(w[(size_t)r*FEAT + i]) : (unsigned short)0;
}

// ---------------- MFMA GEMM: C[M,128] = act(A @ Wb^T + bias) ----------------
// grid = ceil(M/(16*RT)), block 256 = 4 waves; wave computes RT row-tiles x 32 cols.
// RT=4: weight rows read once per 64 output rows (4x amortization vs RT=1).
template<int KB, int RT, bool ABF16, bool BIAS, int ACT, bool OBF16>
__global__ __launch_bounds__(256) void k_gemm(const void* __restrict__ Ap, int lda,
        const unsigned short* __restrict__ Wp, int ldw,
        const float* __restrict__ bias, void* __restrict__ Cp, int M)
{
  int tid = threadIdx.x, wave = tid >> 6, lane = tid & 63;
  int m = lane & 15, quad = lane >> 4;
  int r0 = blockIdx.x * (16*RT);
  bf8 a[RT][KB];
  #pragma unroll
  for(int rt=0; rt<RT; rt++){
    int row = r0 + rt*16 + m;
    if (ABF16){
      const unsigned short* base = (const unsigned short*)Ap + (size_t)row*lda + quad*8;
      #pragma unroll
      for(int kb=0;kb<KB;kb++) a[rt][kb] = *(const bf8*)(base + kb*32);
    } else {
      const float* base = (const float*)Ap + (size_t)row*lda + quad*8;
      #pragma unroll
      for(int kb=0;kb<KB;kb++) a[rt][kb] = cvt8(base + kb*32);
    }
  }
  int c0 = wave * 32;
  #pragma unroll
  for(int ct=0;ct<2;ct++){
    int n = c0 + ct*16 + m;
    const unsigned short* wb = Wp + (size_t)n*ldw + quad*8;
    bf8 b[KB];
    #pragma unroll
    for(int kb=0;kb<KB;kb++) b[kb] = *(const bf8*)(wb + kb*32);
    float bv = BIAS ? bias[n] : 0.f;
    #pragma unroll
    for(int rt=0;rt<RT;rt++){
      f4 acc = {0.f,0.f,0.f,0.f};
      #pragma unroll
      for(int kb=0;kb<KB;kb++)
        acc = __builtin_amdgcn_mfma_f32_16x16x32_bf16(a[rt][kb], b[kb], acc, 0, 0, 0);
      #pragma unroll
      for(int i=0;i<4;i++){
        int row = r0 + rt*16 + quad*4 + i;
        if (row < M){
          float v = acc[i] + bv;
          if (ACT == 1) v = lk(v);
          if (OBF16) ((unsigned short*)Cp)[(size_t)row*H + n] = f2b(v);
          else       ((float*)Cp)[(size_t)row*H + n] = v;
        }
      }
    }
  }
}

// ---------------- fused MFMA GRU, register gates (no LDS): Out = relu(gru(Xin,Hid)) ----------------
// Block = 16 rows. Wave w owns cols [w*32,w*32+32) for ALL 3 gates (6 ct tiles:
// gate g in {r,z,n}, half h: n = g*128 + w*32 + h*16). Gate math fully register-local.
// Out may alias Hid: all Hid reads happen before the barrier; stores after.
__global__ __launch_bounds__(256) void k_gru(const float* __restrict__ Xin,
      const float* __restrict__ Hid, float* __restrict__ Out,
      const unsigned short* __restrict__ Wi, const unsigned short* __restrict__ Wh,
      const float* __restrict__ bi, const float* __restrict__ bh_)
{
  int tid = threadIdx.x, wave = tid >> 6, lane = tid & 63;
  int m = lane & 15, quad = lane >> 4;
  int r0 = blockIdx.x * 16;
  bf8 ax[4], ah[4];
  const float* xb = Xin + (size_t)(r0+m)*H + quad*8;
  const float* hb = Hid + (size_t)(r0+m)*H + quad*8;
  #pragma unroll
  for(int kb=0;kb<4;kb++){
    ax[kb] = cvt8(xb + kb*32);
    ah[kb] = cvt8(hb + kb*32);
  }
  float hv[2][4];
  #pragma unroll
  for(int half=0; half<2; half++){
    int col = wave*32 + half*16 + m;
    #pragma unroll
    for(int i=0;i<4;i++) hv[half][i] = Hid[(size_t)(r0+quad*4+i)*H + col];
  }
  __syncthreads();   // Hid fully read before any Out store (alias safety)
  f4 gi[6], gh[6];
  #pragma unroll
  for(int t=0;t<6;t++){
    int gate = t >> 1, half = t & 1;
    int n = gate*128 + wave*32 + half*16 + m;
    const unsigned short* wib = Wi + (size_t)n*H + quad*8;
    const unsigned short* whb = Wh + (size_t)n*H + quad*8;
    f4 ai = {0.f,0.f,0.f,0.f}, ahh = {0.f,0.f,0.f,0.f};
    #pragma unroll
    for(int kb=0;kb<4;kb++){
      ai  = __builtin_amdgcn_mfma_f32_16x16x32_bf16(ax[kb], *(const bf8*)(wib + kb*32), ai, 0,0,0);
      ahh = __builtin_amdgcn_mfma_f32_16x16x32_bf16(ah[kb], *(const bf8*)(whb + kb*32), ahh, 0,0,0);
    }
    gi[t] = ai; gh[t] = ahh;
  }
  #pragma unroll
  for(int half=0; half<2; half++){
    int col = wave*32 + half*16 + m;
    float bir = bi[col], biz = bi[col+128], bin = bi[col+256];
    float bhr = bh_[col], bhz = bh_[col+128], bhn = bh_[col+256];
    #pragma unroll
    for(int i=0;i<4;i++){
      float rg = sgm(gi[0+half][i] + bir + gh[0+half][i] + bhr);
      float zg = sgm(gi[2+half][i] + biz + gh[2+half][i] + bhz);
      float ng = tanhf(gi[4+half][i] + bin + rg*(gh[4+half][i] + bhn));
      float o = (1.f - zg)*ng + zg*hv[half][i];
      Out[(size_t)(r0+quad*4+i)*H + col] = fmaxf(o, 0.f);
    }
  }
}

// ---------------- row dot products ----------------
template<bool ABF16, bool TWO>
__global__ __launch_bounds__(256) void k_rowdot(const void* __restrict__ Ap,
    const float* __restrict__ v1, const float* __restrict__ v2,
    float* __restrict__ o1, float* __restrict__ o2, int M)
{
  int idx = blockIdx.x*4 + (threadIdx.x >> 6);
  if (idx >= M) return;
  int lane = threadIdx.x & 63;
  int h0 = lane*2;
  float a0, a1;
  if (ABF16){
    unsigned int q = *(const unsigned int*)((const unsigned short*)Ap + (size_t)idx*H + h0);
    a0 = b2f((unsigned short)(q & 0xffffu)); a1 = b2f((unsigned short)(q >> 16));
  } else {
    const float* p = (const float*)Ap + (size_t)idx*H + h0;
    a0 = p[0]; a1 = p[1];
  }
  float p1 = a0*v1[h0] + a1*v1[h0+1];
  p1 = wsum(p1);
  if (lane == 0) o1[idx] = p1;
  if (TWO){
    float p2 = a0*v2[h0] + a1*v2[h0+1];
    p2 = wsum(p2);
    if (lane == 0) o2[idx] = p2;
  }
}

// ---------------- GATEConv: single-pass online-softmax aggregation ----------------
// Wave per dst node; 4 edge-groups of 16 lanes; lane handles 8 cols (bf16 16B loads).
__global__ __launch_bounds__(256) void k_gate_agg(
   const int* __restrict__ ei, const float* __restrict__ eattr,
   const float* __restrict__ gcW, const float* __restrict__ attl,
   const float* __restrict__ r, const unsigned short* __restrict__ u,
   const unsigned short* __restrict__ x2, const float* __restrict__ gbias,
   const int* __restrict__ off, const int* __restrict__ perm,
   float* __restrict__ hout)
{
  __shared__ float W1e_s[H*EDIM];   // [col][j]
  int tid = threadIdx.x;
  for(int i=tid;i<H*EDIM;i+=256) W1e_s[i] = gcW[(i/EDIM)*(H+EDIM) + H + (i%EDIM)];
  __syncthreads();
  int wave = tid >> 6, lane = tid & 63;
  int grp = lane >> 4, sub = lane & 15;
  int n = blockIdx.x*4 + wave;
  if (n >= NND) return;
  int o0 = off[n], deg = off[n+1] - o0;
  int c0 = sub*8;
  float attl8[8];
  #pragma unroll
  for(int c=0;c<8;c++) attl8[c] = attl[c0+c];
  float rn = r[n];
  float mx = -3.4e38f, S = 0.f;
  float acc[8] = {0,0,0,0,0,0,0,0};
  for(int base=0; base<deg; base+=64){
    int cnt = min(deg - base, 64);
    int e_l = 0, s_l = 0;
    if (lane < cnt){ e_l = perm[o0 + base + lane]; s_l = ei[e_l]; }
    #pragma unroll 1
    for(int k=0;k<16;k++){
      int l = grp + k*4;
      if (l >= cnt) break;
      int e = __shfl(e_l, l);
      int s = __shfl(s_l, l);
      const float* ep = eattr + (size_t)e*EDIM;
      bf8 uv = *(const bf8*)(u  + (size_t)s*H + c0);
      bf8 xv = *(const bf8*)(x2 + (size_t)s*H + c0);
      float p = 0.f;
      #pragma unroll
      for(int c=0;c<8;c++){
        float ve = 0.f;
        #pragma unroll
        for(int j=0;j<EDIM;j++) ve += ep[j] * W1e_s[(c0+c)*EDIM + j];
        float t = lk(b2f((unsigned short)uv[c]) + ve);
        p += t * attl8[c];
      }
      #pragma unroll
      for(int o=1;o<16;o<<=1) p += __shfl_xor(p, o);   // reduce within 16-lane group
      float araw = lk(p + rn);
      float mnew = fmaxf(mx, araw);
      float sc = __expf(mx - mnew);
      float w  = __expf(araw - mnew);
      S = S*sc + w;
      #pragma unroll
      for(int c=0;c<8;c++) acc[c] = acc[c]*sc + w*b2f((unsigned short)xv[c]);
      mx = mnew;
    }
  }
  // merge 4 groups (softmax-partial combine)
  #pragma unroll
  for(int o=16;o<64;o<<=1){
    float mo = __shfl_xor(mx, o);
    float So = __shfl_xor(S, o);
    float mnew = fmaxf(mx, mo);
    float sa = __expf(mx - mnew), sb = __expf(mo - mnew);
    S = S*sa + So*sb;
    #pragma unroll
    for(int c=0;c<8;c++){
      float ao = __shfl_xor(acc[c], o);
      acc[c] = acc[c]*sa + ao*sb;
    }
    mx = mnew;
  }
  float inv = 1.f/(S + 1e-16f);
  if (grp == 0){
    #pragma unroll
    for(int c=0;c<8;c++)
      hout[(size_t)n*H + c0 + c] = eluf(acc[c]*inv + gbias[c0+c]);
  }
}

// ---------------- atom GATConv: single-pass online-softmax aggregation ----------------
__global__ __launch_bounds__(256) void k_atom_agg(
    const int* __restrict__ ei, const float* __restrict__ s1, const float* __restrict__ s2,
    const unsigned short* __restrict__ xl, const float* __restrict__ abias,
    const int* __restrict__ off, const int* __restrict__ perm,
    float* __restrict__ hout)
{
  int tid = threadIdx.x, wave = tid >> 6, lane = tid & 63;
  int grp = lane >> 4, sub = lane & 15;
  int n = blockIdx.x*4 + wave;
  if (n >= NND) return;
  int o0 = off[n], deg = off[n+1] - o0;
  int c0 = sub*8;
  float s2n = s2[n];
  float mx = -3.4e38f, S = 0.f;
  float acc[8] = {0,0,0,0,0,0,0,0};
  for(int base=0; base<deg; base+=64){
    int cnt = min(deg - base, 64);
    int s_l = 0; float ar_l = 0.f;
    if (lane < cnt){ int e = perm[o0 + base + lane]; s_l = ei[e]; ar_l = lk(s1[s_l] + s2n); }
    #pragma unroll 1
    for(int k=0;k<16;k++){
      int l = grp + k*4;
      if (l >= cnt) break;
      int s = __shfl(s_l, l);
      float araw = __shfl(ar_l, l);
      bf8 xv = *(const bf8*)(xl + (size_t)s*H + c0);
      float mnew = fmaxf(mx, araw);
      float sc = __expf(mx - mnew);
      float w  = __expf(araw - mnew);
      S = S*sc + w;
      #pragma unroll
      for(int c=0;c<8;c++) acc[c] = acc[c]*sc + w*b2f((unsigned short)xv[c]);
      mx = mnew;
    }
  }
  #pragma unroll
  for(int o=16;o<64;o<<=1){
    float mo = __shfl_xor(mx, o);
    float So = __shfl_xor(S, o);
    float mnew = fmaxf(mx, mo);
    float sa = __expf(mx - mnew), sb = __expf(mo - mnew);
    S = S*sa + So*sb;
    #pragma unroll
    for(int c=0;c<8;c++){
      float ao = __shfl_xor(acc[c], o);
      acc[c] = acc[c]*sa + ao*sb;
    }
    mx = mnew;
  }
  float inv = 1.f/(S + 1e-16f);
  if (grp == 0){
    #pragma unroll
    for(int c=0;c<8;c++)
      hout[(size_t)n*H + c0 + c] = eluf(acc[c]*inv + abias[c0+c]);
  }
}

// ---------------- graph readout: out0 = relu(segment_sum(xh)) ----------------
__global__ __launch_bounds__(256) void k_seg0(const float* __restrict__ xh, const int* __restrict__ goff,
                                              float* __restrict__ outg)
{
  int g = blockIdx.x*4 + (threadIdx.x >> 6);
  if (g >= NG) return;
  int lane = threadIdx.x & 63;
  int gs = goff[g], ge = goff[g+1];
  int h0 = lane*2;
  float a0 = 0.f, a1 = 0.f;
  for(int n=gs;n<ge;n++){
    const float* p = xh + (size_t)n*H + h0;
    a0 += p[0]; a1 += p[1];
  }
  outg[(size_t)g*H + h0]   = fmaxf(a0, 0.f);
  outg[(size_t)g*H + h0+1] = fmaxf(a1, 0.f);
}

// ---------------- molecule attention: single-pass online softmax (wave per graph) ----------------
__global__ __launch_bounds__(256) void k_mol_agg(const float* __restrict__ asrc, const float* __restrict__ d,
    const unsigned short* __restrict__ xm, const int* __restrict__ goff,
    const float* __restrict__ mbias, float* __restrict__ hmol)
{
  int tid = threadIdx.x, wave = tid >> 6, lane = tid & 63;
  int grp = lane >> 4, sub = lane & 15;
  int g = blockIdx.x*4 + wave;
  if (g >= NG) return;
  int gs = goff[g], num = goff[g+1] - gs;
  int c0 = sub*8;
  float dg = d[g];
  float mx = -3.4e38f, S = 0.f;
  float acc[8] = {0,0,0,0,0,0,0,0};
  for(int base=0; base<num; base+=64){
    int cnt = min(num - base, 64);
    float ar_l = 0.f;
    if (lane < cnt) ar_l = lk(asrc[gs + base + lane] + dg);
    #pragma unroll 1
    for(int k=0;k<16;k++){
      int l = grp + k*4;
      if (l >= cnt) break;
      float araw = __shfl(ar_l, l);
      int node = gs + base + l;
      bf8 xv = *(const bf8*)(xm + (size_t)node*H + c0);
      float mnew = fmaxf(mx, araw);
      float sc = __expf(mx - mnew);
      float w  = __expf(araw - mnew);
      S = S*sc + w;
      #pragma unroll
      for(int c=0;c<8;c++) acc[c] = acc[c]*sc + w*b2f((unsigned short)xv[c]);
      mx = mnew;
    }
  }
  #pragma unroll
  for(int o=16;o<64;o<<=1){
    float mo = __shfl_xor(mx, o);
    float So = __shfl_xor(S, o);
    float mnew = fmaxf(mx, mo);
    float sa = __expf(mx - mnew), sb = __expf(mo - mnew);
    S = S*sa + So*sb;
    #pragma unroll
    for(int c=0;c<8;c++){
      float ao = __shfl_xor(acc[c], o);
      acc[c] = acc[c]*sa + ao*sb;
    }
    mx = mnew;
  }
  float inv = 1.f/(S + 1e-16f);
  if (grp == 0){
    #pragma unroll
    for(int c=0;c<8;c++)
      hmol[(size_t)g*H + c0 + c] = eluf(acc[c]*inv + mbias[c0+c]);
  }
}

// ---------------- classifier head (wave per graph) -> FP32 output ----------------
__global__ __launch_bounds__(256) void k_cls(const float* __restrict__ emb,
   const float* __restrict__ W1, const float* __restrict__ b1,
   const float* __restrict__ W2, const float* __restrict__ b2,
   float* __restrict__ outp)
{
  __shared__ float W1t[H*64];   // [h][l]
  int tid = threadIdx.x;
  for(int i=tid;i<64*H;i+=256){
    int l = i >> 7, hh = i & 127;
    W1t[hh*64 + l] = W1[i];
  }
  __syncthreads();
  int wave = tid >> 6, lane = tid & 63;
  int g = blockIdx.x*4 + wave;
  if (g >= NG) return;
  const float* er = emb + (size_t)g*H;
  float acc = 0.f;
  for(int hh=0;hh<H;hh++) acc += er[hh] * W1t[hh*64 + lane];
  float hid = fmaxf(acc + b1[lane], 0.f);
  float p = hid * W2[lane];
  p = wsum(p);
  if (lane == 0) outp[g] = p + b2[0];
}

// =====================================================================================
extern "C" void kernel_launch(void* const* d_in, const int* in_sizes, int n_in,
                              void* d_out, int out_size, void* d_ws, size_t ws_size,
                              hipStream_t stream)
{
  const float* x      = (const float*)d_in[0];
  const float* eattr  = (const float*)d_in[1];
  const float* lin1W  = (const float*)d_in[2];
  const float* lin1b  = (const float*)d_in[3];
  const float* gcW    = (const float*)d_in[4];
  const float* gcatl  = (const float*)d_in[5];
  const float* gcatr  = (const float*)d_in[6];
  const float* gcW2   = (const float*)d_in[7];
  const float* gcb    = (const float*)d_in[8];
  const float* g0Wi   = (const float*)d_in[9];
  const float* g0Wh   = (const float*)d_in[10];
  const float* g0bi   = (const float*)d_in[11];
  const float* g0bh   = (const float*)d_in[12];
  const float* aW     = (const float*)d_in[13];
  const float* aas    = (const float*)d_in[14];
  const float* aad    = (const float*)d_in[15];
  const float* ab     = (const float*)d_in[16];
  const float* agWi   = (const float*)d_in[17];
  const float* agWh   = (const float*)d_in[18];
  const float* agbi   = (const float*)d_in[19];
  const float* agbh   = (const float*)d_in[20];
  const float* mW     = (const float*)d_in[21];
  const float* mas    = (const float*)d_in[22];
  const float* mad    = (const float*)d_in[23];
  const float* mb     = (const float*)d_in[24];
  const float* mgWi   = (const float*)d_in[25];
  const float* mgWh   = (const float*)d_in[26];
  const float* mgbi   = (const float*)d_in[27];
  const float* mgbh   = (const float*)d_in[28];
  const float* l2W    = (const float*)d_in[29];
  const float* l2b    = (const float*)d_in[30];
  const float* cW1    = (const float*)d_in[31];
  const float* cb1    = (const float*)d_in[32];
  const float* cW2    = (const float*)d_in[33];
  const float* cb2    = (const float*)d_in[34];
  const int* ei    = (const int*)d_in[35];
  const int* batch = (const int*)d_in[36];
  float* outp = (float*)d_out;

  char* p = (char*)d_ws;
  auto alloc = [&](size_t sz)->void*{ void* q = (void*)p; p += (sz + 511) & ~(size_t)511; return q; };
  float* x0            = (float*)alloc((size_t)NND*H*4);
  unsigned short* bu   = (unsigned short*)alloc((size_t)NND*H*2);  // bf16 (gather target)
  unsigned short* bx2  = (unsigned short*)alloc((size_t)NND*H*2);  // bf16 (gather target)
  float* xh            = (float*)alloc((size_t)NND*H*4);
  float* bh            = (float*)alloc((size_t)NND*H*4);
  unsigned short* xm   = (unsigned short*)x0;   // alias: x0 dead after first k_gru
  unsigned short* xp   = (unsigned short*)bh;   // alias: bh first written at k_gate_agg (lin1 reads xp before)
  float* rbuf          = (float*)alloc((size_t)NND*4);
  float* s1            = (float*)alloc((size_t)NND*4);
  float* s2            = (float*)alloc((size_t)NND*4);
  float* asrc          = (float*)alloc((size_t)NND*4);
  int* deg             = (int*)alloc((size_t)NND*4);
  int* off             = (int*)alloc((size_t)(NND+1)*4);
  int* cursor          = (int*)alloc((size_t)NND*4);
  int* perm            = (int*)alloc((size_t)NED*4);
  int* bsum            = (int*)alloc((size_t)(NBS+1)*4);
  int* goff            = (int*)alloc((size_t)(NG+1)*4);
  float* outg          = (float*)alloc((size_t)NG*H*4);
  float* hmol          = (float*)alloc((size_t)NG*H*4);
  float* om            = (float*)alloc((size_t)NG*H*4);
  float* emb           = (float*)alloc((size_t)NG*H*4);
  float* dgb           = (float*)alloc((size_t)NG*4);
  // bf16 weights (~1 MB)
  unsigned short* wp     = (unsigned short*)alloc((size_t)H*FEATP*2);
  unsigned short* gcWnb  = (unsigned short*)alloc((size_t)H*H*2);
  unsigned short* gcW2b  = (unsigned short*)alloc((size_t)H*H*2);
  unsigned short* g0Wib  = (unsigned short*)alloc((size_t)3*H*H*2);
  unsigned short* g0Whb  = (unsigned short*)alloc((size_t)3*H*H*2);
  unsigned short* aWb    = (unsigned short*)alloc((size_t)2*H*H*2);
  unsigned short* agWib  = (unsigned short*)alloc((size_t)2*3*H*H*2);
  unsigned short* agWhb  = (unsigned short*)alloc((size_t)2*3*H*H*2);
  unsigned short* mWb    = (unsigned short*)alloc((size_t)H*H*2);
  unsigned short* l2Wb   = (unsigned short*)alloc((size_t)H*H*2);
  unsigned short* mgWib  = (unsigned short*)alloc((size_t)3*H*H*2);
  unsigned short* mgWhb  = (unsigned short*)alloc((size_t)3*H*H*2);

  const int HH = H*H, H3H = 3*H*H;
  k_padw <<<32,256,0,stream>>>(lin1W, wp);
  k_cvtw2<<<(HH+255)/256,256,0,stream>>>(gcW, H+EDIM, gcWnb, H, HH);
  k_cvtw <<<(HH+255)/256,256,0,stream>>>(gcW2, gcW2b, HH);
  k_cvtw <<<(H3H+255)/256,256,0,stream>>>(g0Wi, g0Wib, H3H);
  k_cvtw <<<(H3H+255)/256,256,0,stream>>>(g0Wh, g0Whb, H3H);
  k_cvtw <<<(2*HH+255)/256,256,0,stream>>>(aW, aWb, 2*HH);
  k_cvtw <<<(2*H3H+255)/256,256,0,stream>>>(agWi, agWib, 2*H3H);
  k_cvtw <<<(2*H3H+255)/256,256,0,stream>>>(agWh, agWhb, 2*H3H);
  k_cvtw <<<(HH+255)/256,256,0,stream>>>(mW, mWb, HH);
  k_cvtw <<<(HH+255)/256,256,0,stream>>>(l2W, l2Wb, HH);
  k_cvtw <<<(H3H+255)/256,256,0,stream>>>(mgWi, mgWib, H3H);
  k_cvtw <<<(H3H+255)/256,256,0,stream>>>(mgWh, mgWhb, H3H);

  // CSR by dst + graph offsets
  hipMemsetAsync(deg, 0, (size_t)NND*4, stream);
  k_hist<<<1563,256,0,stream>>>(ei, deg);
  k_scan1<<<NBS,256,0,stream>>>(deg, off, bsum);
  k_scan2<<<1,512,0,stream>>>(bsum);
  k_scan3<<<NBS,256,0,stream>>>(off, bsum, cursor);
  k_scatter<<<1563,256,0,stream>>>(ei, cursor, perm);
  k_gstart<<<NBS,256,0,stream>>>(batch, goff);

  const int GB = (NND + 63)/64;   // gemm blocks (RT=4)
  // lin1 + leaky -> x0 fp32
  k_padx<<<25000,256,0,stream>>>(x, xp);
  k_gemm<5,4,true,true,1,false><<<GB,256,0,stream>>>(xp, FEATP, wp, FEATP, lin1b, x0, NND);

  // GATEConv
  k_rowdot<false,false><<<25000,256,0,stream>>>(x0, gcatr, nullptr, rbuf, nullptr, NND);
  k_gemm<4,4,false,false,0,true><<<GB,256,0,stream>>>(x0, H, gcWnb, H, nullptr, bu, NND);
  k_gemm<4,4,false,false,0,true><<<GB,256,0,stream>>>(x0, H, gcW2b, H, nullptr, bx2, NND);
  k_gate_agg<<<25000,256,0,stream>>>(ei, eattr, gcW, gcatl, rbuf, bu, bx2, gcb, off, perm, bh);
  k_gru<<<NND/16,256,0,stream>>>(bh, x0, xh, g0Wib, g0Whb, g0bi, g0bh);

  // atom GAT layers
  for(int l=0;l<2;l++){
    k_gemm<4,4,false,false,0,true><<<GB,256,0,stream>>>(xh, H, aWb + (size_t)l*HH, H, nullptr, bu, NND);
    k_rowdot<true,true><<<25000,256,0,stream>>>(bu, aas + l*H, aad + l*H, s1, s2, NND);
    k_atom_agg<<<25000,256,0,stream>>>(ei, s1, s2, bu, ab + l*H, off, perm, bh);
    k_gru<<<NND/16,256,0,stream>>>(bh, xh, xh, agWib + (size_t)l*H3H, agWhb + (size_t)l*H3H,
                                   agbi + l*3*H, agbh + l*3*H);
  }

  // molecule readout
  k_seg0<<<NG/4,256,0,stream>>>(xh, goff, outg);
  k_gemm<4,4,false,false,0,true><<<GB,256,0,stream>>>(xh, H, mWb, H, nullptr, xm, NND);
  k_rowdot<true,false><<<25000,256,0,stream>>>(xm, mas, nullptr, asrc, nullptr, NND);
  for(int t=0;t<2;t++){
    k_gemm<4,4,false,false,0,false><<<(NG+63)/64,256,0,stream>>>(outg, H, mWb, H, nullptr, om, NG);
    k_rowdot<false,false><<<NG/4,256,0,stream>>>(om, mad, nullptr, dgb, nullptr, NG);
    k_mol_agg<<<NG/4,256,0,stream>>>(asrc, dgb, xm, goff, mb, hmol);
    k_gru<<<NG/16,256,0,stream>>>(hmol, outg, outg, mgWib, mgWhb, mgbi, mgbh);
  }

  // head
  k_gemm<4,4,false,true,0,false><<<(NG+63)/64,256,0,stream>>>(outg, H, l2Wb, H, l2b, emb, NG);
  k_cls<<<NG/4,256,0,stream>>>(emb, cW1, cb1, cW2, cb2, outp);
}

// Round 7
// 1105.205 us; speedup vs baseline: 18.1984x; 1.2769x over previous
//
#include <hip/hip_runtime.h>

#define NND 100000   // nodes
#define NED 400000   // edges
#define FEAT 143
#define FEATP 160
#define EDIM 6
#define H 128
#define NG 4096      // graphs
#define NBS 391      // ceil(NND/256)

typedef __attribute__((ext_vector_type(8))) short bf8;
typedef __attribute__((ext_vector_type(4))) float f4;

__device__ __forceinline__ float b2f(unsigned short u){
  unsigned int x = ((unsigned int)u) << 16;
  return __builtin_bit_cast(float, x);
}
__device__ __forceinline__ unsigned short f2b(float f){
  unsigned int u = __builtin_bit_cast(unsigned int, f);
  u = u + 0x7fffu + ((u >> 16) & 1u);   // RNE
  return (unsigned short)(u >> 16);
}
__device__ __forceinline__ float lk(float v){ return v >= 0.f ? v : 0.01f*v; }
__device__ __forceinline__ float eluf(float v){ return v > 0.f ? v : __expf(v) - 1.f; }
__device__ __forceinline__ float sgm(float v){ return 1.f/(1.f + __expf(-v)); }
__device__ __forceinline__ float wsum(float v){
  #pragma unroll
  for(int o=32;o>0;o>>=1) v += __shfl_xor(v,o);
  return v;
}
// 16B-aligned fp32x8 -> bf16x8
__device__ __forceinline__ bf8 cvt8(const float* p){
  f4 a = *(const f4*)p;
  f4 b = *(const f4*)(p+4);
  bf8 t;
  t[0]=(short)f2b(a[0]); t[1]=(short)f2b(a[1]); t[2]=(short)f2b(a[2]); t[3]=(short)f2b(a[3]);
  t[4]=(short)f2b(b[0]); t[5]=(short)f2b(b[1]); t[6]=(short)f2b(b[2]); t[7]=(short)f2b(b[3]);
  return t;
}

// ---------------- weight fp32 -> bf16 MFMA-fragment order ----------------
// dst[((nt*KB+kb)*64 + lane)*8 + j] = W[nt*16 + (lane&15)][kb*32 + (lane>>4)*8 + j]
// (zero-padded for k >= srcK). Makes every B-operand load a contiguous 1KB stream.
__global__ __launch_bounds__(256) void k_wfrag(const float* __restrict__ src, int lds, int srcK,
                                               unsigned short* __restrict__ dst, int NT, int KB){
  int i = blockIdx.x*256 + threadIdx.x;
  int total = NT*KB*512;
  if (i >= total) return;
  int j = i & 7, lane = (i>>3) & 63, kb = (i>>9) % KB, nt = i/(KB*512);
  int n = nt*16 + (lane & 15), k = kb*32 + (lane>>4)*8 + j;
  dst[i] = (k < srcK) ? f2b(src[(size_t)n*lds + k]) : (unsigned short)0;
}

// ---------------- CSR build (counting sort of edges by dst) ----------------
__global__ __launch_bounds__(256) void k_hist(const int* __restrict__ ei, int* __restrict__ deg){
  int e = blockIdx.x*256 + threadIdx.x;
  if (e < NED) atomicAdd(&deg[ei[NED + e]], 1);
}
__global__ __launch_bounds__(256) void k_scan1(const int* __restrict__ deg, int* __restrict__ off, int* __restrict__ bsum){
  __shared__ int s[256];
  int i = blockIdx.x*256 + threadIdx.x;
  int v = (i < NND) ? deg[i] : 0;
  s[threadIdx.x] = v; __syncthreads();
  for(int o=1;o<256;o<<=1){
    int t = 0; if (threadIdx.x >= o) t = s[threadIdx.x - o];
    __syncthreads(); s[threadIdx.x] += t; __syncthreads();
  }
  if (i < NND) off[i] = s[threadIdx.x] - v;
  if (threadIdx.x == 255) bsum[blockIdx.x] = s[255];
}
__global__ __launch_bounds__(512) void k_scan2(int* __restrict__ bsum){
  __shared__ int s[512];
  int t = threadIdx.x;
  int v = (t < NBS) ? bsum[t] : 0;
  s[t] = v; __syncthreads();
  for(int o=1;o<512;o<<=1){
    int x = 0; if (t >= o) x = s[t - o];
    __syncthreads(); s[t] += x; __syncthreads();
  }
  if (t < NBS) bsum[t] = s[t] - v;
  if (t == 511) bsum[NBS] = s[511];
}
__global__ __launch_bounds__(256) void k_scan3(int* __restrict__ off, const int* __restrict__ bsum, int* __restrict__ cursor){
  int i = blockIdx.x*256 + threadIdx.x;
  if (i < NND){
    int v = off[i] + bsum[blockIdx.x];
    off[i] = v; cursor[i] = v;
  }
  if (i == 0) off[NND] = bsum[NBS];
}
__global__ __launch_bounds__(256) void k_scatter(const int* __restrict__ ei, int* __restrict__ cursor, int* __restrict__ perm){
  int e = blockIdx.x*256 + threadIdx.x;
  if (e < NED){
    int p = atomicAdd(&cursor[ei[NED + e]], 1);
    perm[p] = e;
  }
}
__global__ __launch_bounds__(256) void k_gstart(const int* __restrict__ batch, int* __restrict__ goff){
  int i = blockIdx.x*256 + threadIdx.x;
  if (i >= NND) return;
  int bi = batch[i];
  int bp = (i > 0) ? batch[i-1] : -1;
  for(int g = bp+1; g <= bi; g++) goff[g] = i;
  if (i == NND-1) for(int g = bi+1; g <= NG; g++) goff[g] = NND;
}

// ---------------- pad + fp32->bf16 for lin1 A (K=143 -> 160) ----------------
__global__ __launch_bounds__(256) void k_padx(const float* __restrict__ x, unsigned short* __restrict__ xp){
  int r = blockIdx.x*4 + (threadIdx.x >> 6);
  int lane = threadIdx.x & 63;
  if (r >= NND) return;
  for(int i = lane; i < FEATP; i += 64)
    xp[(size_t)r*FEATP + i] = (i < FEAT) ? f2b(x[(size_t)r*FEAT + i]) : (unsigned short)0;
}

// ---------------- MFMA GEMM: C[M,128] = act(A @ W^T + bias), W in fragment order ----------------
// grid = ceil(M/(16*RT)), block 256 = 4 waves; wave computes RT row-tiles x 32 cols.
template<int KB, int RT, bool ABF16, bool BIAS, int ACT, bool OBF16>
__global__ __launch_bounds__(256) void k_gemm(const void* __restrict__ Ap, int lda,
        const unsigned short* __restrict__ Wf,
        const float* __restrict__ bias, void* __restrict__ Cp, int M)
{
  int tid = threadIdx.x, wave = tid >> 6, lane = tid & 63;
  int m = lane & 15, quad = lane >> 4;
  int r0 = blockIdx.x * (16*RT);
  bf8 a[RT][KB];
  #pragma unroll
  for(int rt=0; rt<RT; rt++){
    int row = r0 + rt*16 + m;
    if (ABF16){
      const unsigned short* base = (const unsigned short*)Ap + (size_t)row*lda + quad*8;
      #pragma unroll
      for(int kb=0;kb<KB;kb++) a[rt][kb] = *(const bf8*)(base + kb*32);
    } else {
      const float* base = (const float*)Ap + (size_t)row*lda + quad*8;
      #pragma unroll
      for(int kb=0;kb<KB;kb++) a[rt][kb] = cvt8(base + kb*32);
    }
  }
  #pragma unroll
  for(int ct=0;ct<2;ct++){
    int nt = wave*2 + ct;
    int n = nt*16 + m;
    const bf8* wf = (const bf8*)Wf + (size_t)nt*KB*64;
    bf8 b[KB];
    #pragma unroll
    for(int kb=0;kb<KB;kb++) b[kb] = wf[kb*64 + lane];
    float bv = BIAS ? bias[n] : 0.f;
    #pragma unroll
    for(int rt=0;rt<RT;rt++){
      f4 acc = {0.f,0.f,0.f,0.f};
      #pragma unroll
      for(int kb=0;kb<KB;kb++)
        acc = __builtin_amdgcn_mfma_f32_16x16x32_bf16(a[rt][kb], b[kb], acc, 0, 0, 0);
      #pragma unroll
      for(int i=0;i<4;i++){
        int row = r0 + rt*16 + quad*4 + i;
        if (row < M){
          float v = acc[i] + bv;
          if (ACT == 1) v = lk(v);
          if (OBF16) ((unsigned short*)Cp)[(size_t)row*H + n] = f2b(v);
          else       ((float*)Cp)[(size_t)row*H + n] = v;
        }
      }
    }
  }
}

// ---------------- fused MFMA GRU v4: Out = relu(gru(Xin,Hid)), 32 rows/block ----------------
// Gates sequential r->n->z; r/z use dual-MFMA single accumulator (gi+gh fused).
// Weights in fragment order (Wif/Whf: NT=24 tiles of [4kb][64lane] bf8).
// Out may alias Hid: A-frags loaded before barrier; stores only after; hv is own-col/row.
__global__ __launch_bounds__(256) void k_gru(const float* __restrict__ Xin,
      const float* __restrict__ Hid, float* __restrict__ Out,
      const unsigned short* __restrict__ Wif, const unsigned short* __restrict__ Whf,
      const float* __restrict__ bi, const float* __restrict__ bh_)
{
  int tid = threadIdx.x, wave = tid >> 6, lane = tid & 63;
  int m = lane & 15, quad = lane >> 4;
  int r0 = blockIdx.x * 32;
  bf8 ax[2][4], ah[2][4];
  #pragma unroll
  for(int rt=0;rt<2;rt++){
    const float* xb = Xin + (size_t)(r0+rt*16+m)*H + quad*8;
    const float* hb = Hid + (size_t)(r0+rt*16+m)*H + quad*8;
    #pragma unroll
    for(int kb=0;kb<4;kb++){
      ax[rt][kb] = cvt8(xb + kb*32);
      ah[rt][kb] = cvt8(hb + kb*32);
    }
  }
  __syncthreads();   // all A-frag reads of (possibly aliased) Hid done before any store
  f4 rg[2][2], ng[2][2];
  // gate r (rows 0..127 of W)
  #pragma unroll
  for(int c=0;c<2;c++){
    int nt = wave*2 + c;
    const bf8* wi = (const bf8*)Wif + (size_t)nt*256;
    const bf8* wh = (const bf8*)Whf + (size_t)nt*256;
    int col = nt*16 + m;
    float bb = bi[col] + bh_[col];
    #pragma unroll
    for(int rt=0;rt<2;rt++){
      f4 acc = {0.f,0.f,0.f,0.f};
      #pragma unroll
      for(int kb=0;kb<4;kb++){
        acc = __builtin_amdgcn_mfma_f32_16x16x32_bf16(ax[rt][kb], wi[kb*64+lane], acc,0,0,0);
        acc = __builtin_amdgcn_mfma_f32_16x16x32_bf16(ah[rt][kb], wh[kb*64+lane], acc,0,0,0);
      }
      #pragma unroll
      for(int i=0;i<4;i++) rg[c][rt][i] = sgm(acc[i] + bb);
    }
  }
  // gate n (rows 256..383): needs separate i/h accs
  #pragma unroll
  for(int c=0;c<2;c++){
    int nt = 16 + wave*2 + c;
    const bf8* wi = (const bf8*)Wif + (size_t)nt*256;
    const bf8* wh = (const bf8*)Whf + (size_t)nt*256;
    int col = (wave*2+c)*16 + m;
    float bin_ = bi[col+256], bhn_ = bh_[col+256];
    #pragma unroll
    for(int rt=0;rt<2;rt++){
      f4 a1 = {0.f,0.f,0.f,0.f}, a2 = {0.f,0.f,0.f,0.f};
      #pragma unroll
      for(int kb=0;kb<4;kb++){
        a1 = __builtin_amdgcn_mfma_f32_16x16x32_bf16(ax[rt][kb], wi[kb*64+lane], a1,0,0,0);
        a2 = __builtin_amdgcn_mfma_f32_16x16x32_bf16(ah[rt][kb], wh[kb*64+lane], a2,0,0,0);
      }
      #pragma unroll
      for(int i=0;i<4;i++)
        ng[c][rt][i] = tanhf(a1[i] + bin_ + rg[c][rt][i]*(a2[i] + bhn_));
    }
  }
  // gate z (rows 128..255) + output
  #pragma unroll
  for(int c=0;c<2;c++){
    int nt = 8 + wave*2 + c;
    const bf8* wi = (const bf8*)Wif + (size_t)nt*256;
    const bf8* wh = (const bf8*)Whf + (size_t)nt*256;
    int col = (wave*2+c)*16 + m;
    float bb = bi[col+128] + bh_[col+128];
    #pragma unroll
    for(int rt=0;rt<2;rt++){
      f4 acc = {0.f,0.f,0.f,0.f};
      #pragma unroll
      for(int kb=0;kb<4;kb++){
        acc = __builtin_amdgcn_mfma_f32_16x16x32_bf16(ax[rt][kb], wi[kb*64+lane], acc,0,0,0);
        acc = __builtin_amdgcn_mfma_f32_16x16x32_bf16(ah[rt][kb], wh[kb*64+lane], acc,0,0,0);
      }
      #pragma unroll
      for(int i=0;i<4;i++){
        float zg = sgm(acc[i] + bb);
        int row = r0 + rt*16 + quad*4 + i;
        float hv = Hid[(size_t)row*H + col];
        float o = (1.f - zg)*ng[c][rt][i] + zg*hv;
        Out[(size_t)row*H + col] = fmaxf(o, 0.f);
      }
    }
  }
}

// ---------------- row dot products ----------------
template<bool ABF16, bool TWO>
__global__ __launch_bounds__(256) void k_rowdot(const void* __restrict__ Ap,
    const float* __restrict__ v1, const float* __restrict__ v2,
    float* __restrict__ o1, float* __restrict__ o2, int M)
{
  int idx = blockIdx.x*4 + (threadIdx.x >> 6);
  if (idx >= M) return;
  int lane = threadIdx.x & 63;
  int h0 = lane*2;
  float a0, a1;
  if (ABF16){
    unsigned int q = *(const unsigned int*)((const unsigned short*)Ap + (size_t)idx*H + h0);
    a0 = b2f((unsigned short)(q & 0xffffu)); a1 = b2f((unsigned short)(q >> 16));
  } else {
    const float* p = (const float*)Ap + (size_t)idx*H + h0;
    a0 = p[0]; a1 = p[1];
  }
  float p1 = a0*v1[h0] + a1*v1[h0+1];
  p1 = wsum(p1);
  if (lane == 0) o1[idx] = p1;
  if (TWO){
    float p2 = a0*v2[h0] + a1*v2[h0+1];
    p2 = wsum(p2);
    if (lane == 0) o2[idx] = p2;
  }
}

// ---------------- GATEConv: single-pass online-softmax aggregation ----------------
__global__ __launch_bounds__(256) void k_gate_agg(
   const int* __restrict__ ei, const float* __restrict__ eattr,
   const float* __restrict__ gcW, const float* __restrict__ attl,
   const float* __restrict__ r, const unsigned short* __restrict__ u,
   const unsigned short* __restrict__ x2, const float* __restrict__ gbias,
   const int* __restrict__ off, const int* __restrict__ perm,
   float* __restrict__ hout)
{
  __shared__ float W1e_s[H*EDIM];   // [col][j]
  int tid = threadIdx.x;
  for(int i=tid;i<H*EDIM;i+=256) W1e_s[i] = gcW[(i/EDIM)*(H+EDIM) + H + (i%EDIM)];
  __syncthreads();
  int wave = tid >> 6, lane = tid & 63;
  int grp = lane >> 4, sub = lane & 15;
  int n = blockIdx.x*4 + wave;
  if (n >= NND) return;
  int o0 = off[n], deg = off[n+1] - o0;
  int c0 = sub*8;
  float attl8[8];
  #pragma unroll
  for(int c=0;c<8;c++) attl8[c] = attl[c0+c];
  float rn = r[n];
  float mx = -3.4e38f, S = 0.f;
  float acc[8] = {0,0,0,0,0,0,0,0};
  for(int base=0; base<deg; base+=64){
    int cnt = min(deg - base, 64);
    int e_l = 0, s_l = 0;
    if (lane < cnt){ e_l = perm[o0 + base + lane]; s_l = ei[e_l]; }
    #pragma unroll 1
    for(int k=0;k<16;k++){
      int l = grp + k*4;
      if (l >= cnt) break;
      int e = __shfl(e_l, l);
      int s = __shfl(s_l, l);
      const float* ep = eattr + (size_t)e*EDIM;
      bf8 uv = *(const bf8*)(u  + (size_t)s*H + c0);
      bf8 xv = *(const bf8*)(x2 + (size_t)s*H + c0);
      float p = 0.f;
      #pragma unroll
      for(int c=0;c<8;c++){
        float ve = 0.f;
        #pragma unroll
        for(int j=0;j<EDIM;j++) ve += ep[j] * W1e_s[(c0+c)*EDIM + j];
        float t = lk(b2f((unsigned short)uv[c]) + ve);
        p += t * attl8[c];
      }
      #pragma unroll
      for(int o=1;o<16;o<<=1) p += __shfl_xor(p, o);
      float araw = lk(p + rn);
      float mnew = fmaxf(mx, araw);
      float sc = __expf(mx - mnew);
      float w  = __expf(araw - mnew);
      S = S*sc + w;
      #pragma unroll
      for(int c=0;c<8;c++) acc[c] = acc[c]*sc + w*b2f((unsigned short)xv[c]);
      mx = mnew;
    }
  }
  #pragma unroll
  for(int o=16;o<64;o<<=1){
    float mo = __shfl_xor(mx, o);
    float So = __shfl_xor(S, o);
    float mnew = fmaxf(mx, mo);
    float sa = __expf(mx - mnew), sb = __expf(mo - mnew);
    S = S*sa + So*sb;
    #pragma unroll
    for(int c=0;c<8;c++){
      float ao = __shfl_xor(acc[c], o);
      acc[c] = acc[c]*sa + ao*sb;
    }
    mx = mnew;
  }
  float inv = 1.f/(S + 1e-16f);
  if (grp == 0){
    #pragma unroll
    for(int c=0;c<8;c++)
      hout[(size_t)n*H + c0 + c] = eluf(acc[c]*inv + gbias[c0+c]);
  }
}

// ---------------- atom GATConv: single-pass online-softmax aggregation ----------------
__global__ __launch_bounds__(256) void k_atom_agg(
    const int* __restrict__ ei, const float* __restrict__ s1, const float* __restrict__ s2,
    const unsigned short* __restrict__ xl, const float* __restrict__ abias,
    const int* __restrict__ off, const int* __restrict__ perm,
    float* __restrict__ hout)
{
  int tid = threadIdx.x, wave = tid >> 6, lane = tid & 63;
  int grp = lane >> 4, sub = lane & 15;
  int n = blockIdx.x*4 + wave;
  if (n >= NND) return;
  int o0 = off[n], deg = off[n+1] - o0;
  int c0 = sub*8;
  float s2n = s2[n];
  float mx = -3.4e38f, S = 0.f;
  float acc[8] = {0,0,0,0,0,0,0,0};
  for(int base=0; base<deg; base+=64){
    int cnt = min(deg - base, 64);
    int s_l = 0; float ar_l = 0.f;
    if (lane < cnt){ int e = perm[o0 + base + lane]; s_l = ei[e]; ar_l = lk(s1[s_l] + s2n); }
    #pragma unroll 1
    for(int k=0;k<16;k++){
      int l = grp + k*4;
      if (l >= cnt) break;
      int s = __shfl(s_l, l);
      float araw = __shfl(ar_l, l);
      bf8 xv = *(const bf8*)(xl + (size_t)s*H + c0);
      float mnew = fmaxf(mx, araw);
      float sc = __expf(mx - mnew);
      float w  = __expf(araw - mnew);
      S = S*sc + w;
      #pragma unroll
      for(int c=0;c<8;c++) acc[c] = acc[c]*sc + w*b2f((unsigned short)xv[c]);
      mx = mnew;
    }
  }
  #pragma unroll
  for(int o=16;o<64;o<<=1){
    float mo = __shfl_xor(mx, o);
    float So = __shfl_xor(S, o);
    float mnew = fmaxf(mx, mo);
    float sa = __expf(mx - mnew), sb = __expf(mo - mnew);
    S = S*sa + So*sb;
    #pragma unroll
    for(int c=0;c<8;c++){
      float ao = __shfl_xor(acc[c], o);
      acc[c] = acc[c]*sa + ao*sb;
    }
    mx = mnew;
  }
  float inv = 1.f/(S + 1e-16f);
  if (grp == 0){
    #pragma unroll
    for(int c=0;c<8;c++)
      hout[(size_t)n*H + c0 + c] = eluf(acc[c]*inv + abias[c0+c]);
  }
}

// ---------------- graph readout: out0 = relu(segment_sum(xh)) ----------------
__global__ __launch_bounds__(256) void k_seg0(const float* __restrict__ xh, const int* __restrict__ goff,
                                              float* __restrict__ outg)
{
  int g = blockIdx.x*4 + (threadIdx.x >> 6);
  if (g >= NG) return;
  int lane = threadIdx.x & 63;
  int gs = goff[g], ge = goff[g+1];
  int h0 = lane*2;
  float a0 = 0.f, a1 = 0.f;
  for(int n=gs;n<ge;n++){
    const float* p = xh + (size_t)n*H + h0;
    a0 += p[0]; a1 += p[1];
  }
  outg[(size_t)g*H + h0]   = fmaxf(a0, 0.f);
  outg[(size_t)g*H + h0+1] = fmaxf(a1, 0.f);
}

// ---------------- molecule attention: single-pass online softmax (wave per graph) ----------------
__global__ __launch_bounds__(256) void k_mol_agg(const float* __restrict__ asrc, const float* __restrict__ d,
    const unsigned short* __restrict__ xm, const int* __restrict__ goff,
    const float* __restrict__ mbias, float* __restrict__ hmol)
{
  int tid = threadIdx.x, wave = tid >> 6, lane = tid & 63;
  int grp = lane >> 4, sub = lane & 15;
  int g = blockIdx.x*4 + wave;
  if (g >= NG) return;
  int gs = goff[g], num = goff[g+1] - gs;
  int c0 = sub*8;
  float dg = d[g];
  float mx = -3.4e38f, S = 0.f;
  float acc[8] = {0,0,0,0,0,0,0,0};
  for(int base=0; base<num; base+=64){
    int cnt = min(num - base, 64);
    float ar_l = 0.f;
    if (lane < cnt) ar_l = lk(asrc[gs + base + lane] + dg);
    #pragma unroll 1
    for(int k=0;k<16;k++){
      int l = grp + k*4;
      if (l >= cnt) break;
      float araw = __shfl(ar_l, l);
      int node = gs + base + l;
      bf8 xv = *(const bf8*)(xm + (size_t)node*H + c0);
      float mnew = fmaxf(mx, araw);
      float sc = __expf(mx - mnew);
      float w  = __expf(araw - mnew);
      S = S*sc + w;
      #pragma unroll
      for(int c=0;c<8;c++) acc[c] = acc[c]*sc + w*b2f((unsigned short)xv[c]);
      mx = mnew;
    }
  }
  #pragma unroll
  for(int o=16;o<64;o<<=1){
    float mo = __shfl_xor(mx, o);
    float So = __shfl_xor(S, o);
    float mnew = fmaxf(mx, mo);
    float sa = __expf(mx - mnew), sb = __expf(mo - mnew);
    S = S*sa + So*sb;
    #pragma unroll
    for(int c=0;c<8;c++){
      float ao = __shfl_xor(acc[c], o);
      acc[c] = acc[c]*sa + ao*sb;
    }
    mx = mnew;
  }
  float inv = 1.f/(S + 1e-16f);
  if (grp == 0){
    #pragma unroll
    for(int c=0;c<8;c++)
      hmol[(size_t)g*H + c0 + c] = eluf(acc[c]*inv + mbias[c0+c]);
  }
}

// ---------------- classifier head (wave per graph) -> FP32 output ----------------
__global__ __launch_bounds__(256) void k_cls(const float* __restrict__ emb,
   const float* __restrict__ W1, const float* __restrict__ b1,
   const float* __restrict__ W2, const float* __restrict__ b2,
   float* __restrict__ outp)
{
  __shared__ float W1t[H*64];   // [h][l]
  int tid = threadIdx.x;
  for(int i=tid;i<64*H;i+=256){
    int l = i >> 7, hh = i & 127;
    W1t[hh*64 + l] = W1[i];
  }
  __syncthreads();
  int wave = tid >> 6, lane = tid & 63;
  int g = blockIdx.x*4 + wave;
  if (g >= NG) return;
  const float* er = emb + (size_t)g*H;
  float acc = 0.f;
  for(int hh=0;hh<H;hh++) acc += er[hh] * W1t[hh*64 + lane];
  float hid = fmaxf(acc + b1[lane], 0.f);
  float p = hid * W2[lane];
  p = wsum(p);
  if (lane == 0) outp[g] = p + b2[0];
}

// =====================================================================================
extern "C" void kernel_launch(void* const* d_in, const int* in_sizes, int n_in,
                              void* d_out, int out_size, void* d_ws, size_t ws_size,
                              hipStream_t stream)
{
  const float* x      = (const float*)d_in[0];
  const float* eattr  = (const float*)d_in[1];
  const float* lin1W  = (const float*)d_in[2];
  const float* lin1b  = (const float*)d_in[3];
  const float* gcW    = (const float*)d_in[4];
  const float* gcatl  = (const float*)d_in[5];
  const float* gcatr  = (const float*)d_in[6];
  const float* gcW2   = (const float*)d_in[7];
  const float* gcb    = (const float*)d_in[8];
  const float* g0Wi   = (const float*)d_in[9];
  const float* g0Wh   = (const float*)d_in[10];
  const float* g0bi   = (const float*)d_in[11];
  const float* g0bh   = (const float*)d_in[12];
  const float* aW     = (const float*)d_in[13];
  const float* aas    = (const float*)d_in[14];
  const float* aad    = (const float*)d_in[15];
  const float* ab     = (const float*)d_in[16];
  const float* agWi   = (const float*)d_in[17];
  const float* agWh   = (const float*)d_in[18];
  const float* agbi   = (const float*)d_in[19];
  const float* agbh   = (const float*)d_in[20];
  const float* mW     = (const float*)d_in[21];
  const float* mas    = (const float*)d_in[22];
  const float* mad    = (const float*)d_in[23];
  const float* mb     = (const float*)d_in[24];
  const float* mgWi   = (const float*)d_in[25];
  const float* mgWh   = (const float*)d_in[26];
  const float* mgbi   = (const float*)d_in[27];
  const float* mgbh   = (const float*)d_in[28];
  const float* l2W    = (const float*)d_in[29];
  const float* l2b    = (const float*)d_in[30];
  const float* cW1    = (const float*)d_in[31];
  const float* cb1    = (const float*)d_in[32];
  const float* cW2    = (const float*)d_in[33];
  const float* cb2    = (const float*)d_in[34];
  const int* ei    = (const int*)d_in[35];
  const int* batch = (const int*)d_in[36];
  float* outp = (float*)d_out;

  char* p = (char*)d_ws;
  auto alloc = [&](size_t sz)->void*{ void* q = (void*)p; p += (sz + 511) & ~(size_t)511; return q; };
  float* x0            = (float*)alloc((size_t)NND*H*4);
  unsigned short* bu   = (unsigned short*)alloc((size_t)NND*H*2);  // bf16 (gather target)
  unsigned short* bx2  = (unsigned short*)alloc((size_t)NND*H*2);  // bf16 (gather target)
  float* xh            = (float*)alloc((size_t)NND*H*4);
  float* bh            = (float*)alloc((size_t)NND*H*4);
  unsigned short* xm   = (unsigned short*)x0;   // alias: x0 dead after first k_gru
  unsigned short* xp   = (unsigned short*)bh;   // alias: bh first written at k_gate_agg (lin1 reads xp before)
  float* rbuf          = (float*)alloc((size_t)NND*4);
  float* s1            = (float*)alloc((size_t)NND*4);
  float* s2            = (float*)alloc((size_t)NND*4);
  float* asrc          = (float*)alloc((size_t)NND*4);
  int* deg             = (int*)alloc((size_t)NND*4);
  int* off             = (int*)alloc((size_t)(NND+1)*4);
  int* cursor          = (int*)alloc((size_t)NND*4);
  int* perm            = (int*)alloc((size_t)NED*4);
  int* bsum            = (int*)alloc((size_t)(NBS+1)*4);
  int* goff            = (int*)alloc((size_t)(NG+1)*4);
  float* outg          = (float*)alloc((size_t)NG*H*4);
  float* hmol          = (float*)alloc((size_t)NG*H*4);
  float* om            = (float*)alloc((size_t)NG*H*4);
  float* emb           = (float*)alloc((size_t)NG*H*4);
  float* dgb           = (float*)alloc((size_t)NG*4);
  // fragment-ordered bf16 weights
  unsigned short* wp     = (unsigned short*)alloc((size_t)8*5*512*2);      // lin1: NT=8, KB=5
  unsigned short* gcWnb  = (unsigned short*)alloc((size_t)H*H*2);
  unsigned short* gcW2b  = (unsigned short*)alloc((size_t)H*H*2);
  unsigned short* g0Wib  = (unsigned short*)alloc((size_t)3*H*H*2);
  unsigned short* g0Whb  = (unsigned short*)alloc((size_t)3*H*H*2);
  unsigned short* aWb    = (unsigned short*)alloc((size_t)2*H*H*2);
  unsigned short* agWib  = (unsigned short*)alloc((size_t)2*3*H*H*2);
  unsigned short* agWhb  = (unsigned short*)alloc((size_t)2*3*H*H*2);
  unsigned short* mWb    = (unsigned short*)alloc((size_t)H*H*2);
  unsigned short* l2Wb   = (unsigned short*)alloc((size_t)H*H*2);
  unsigned short* mgWib  = (unsigned short*)alloc((size_t)3*H*H*2);
  unsigned short* mgWhb  = (unsigned short*)alloc((size_t)3*H*H*2);

  const int HH = H*H, H3H = 3*H*H;
  // fragment-order conversions: grid = NT*KB*512/256
  k_wfrag<<<80 ,256,0,stream>>>(lin1W, FEAT, FEAT, wp, 8, 5);
  k_wfrag<<<64 ,256,0,stream>>>(gcW, H+EDIM, H, gcWnb, 8, 4);
  k_wfrag<<<64 ,256,0,stream>>>(gcW2, H, H, gcW2b, 8, 4);
  k_wfrag<<<192,256,0,stream>>>(g0Wi, H, H, g0Wib, 24, 4);
  k_wfrag<<<192,256,0,stream>>>(g0Wh, H, H, g0Whb, 24, 4);
  for(int l=0;l<2;l++){
    k_wfrag<<<64 ,256,0,stream>>>(aW + (size_t)l*HH, H, H, aWb + (size_t)l*HH, 8, 4);
    k_wfrag<<<192,256,0,stream>>>(agWi + (size_t)l*H3H, H, H, agWib + (size_t)l*H3H, 24, 4);
    k_wfrag<<<192,256,0,stream>>>(agWh + (size_t)l*H3H, H, H, agWhb + (size_t)l*H3H, 24, 4);
  }
  k_wfrag<<<64 ,256,0,stream>>>(mW, H, H, mWb, 8, 4);
  k_wfrag<<<64 ,256,0,stream>>>(l2W, H, H, l2Wb, 8, 4);
  k_wfrag<<<192,256,0,stream>>>(mgWi, H, H, mgWib, 24, 4);
  k_wfrag<<<192,256,0,stream>>>(mgWh, H, H, mgWhb, 24, 4);

  // CSR by dst + graph offsets
  hipMemsetAsync(deg, 0, (size_t)NND*4, stream);
  k_hist<<<1563,256,0,stream>>>(ei, deg);
  k_scan1<<<NBS,256,0,stream>>>(deg, off, bsum);
  k_scan2<<<1,512,0,stream>>>(bsum);
  k_scan3<<<NBS,256,0,stream>>>(off, bsum, cursor);
  k_scatter<<<1563,256,0,stream>>>(ei, cursor, perm);
  k_gstart<<<NBS,256,0,stream>>>(batch, goff);

  const int GB = (NND + 63)/64;   // gemm blocks (RT=4)
  // lin1 + leaky -> x0 fp32
  k_padx<<<25000,256,0,stream>>>(x, xp);
  k_gemm<5,4,true,true,1,false><<<GB,256,0,stream>>>(xp, FEATP, wp, lin1b, x0, NND);

  // GATEConv
  k_rowdot<false,false><<<25000,256,0,stream>>>(x0, gcatr, nullptr, rbuf, nullptr, NND);
  k_gemm<4,4,false,false,0,true><<<GB,256,0,stream>>>(x0, H, gcWnb, nullptr, bu, NND);
  k_gemm<4,4,false,false,0,true><<<GB,256,0,stream>>>(x0, H, gcW2b, nullptr, bx2, NND);
  k_gate_agg<<<25000,256,0,stream>>>(ei, eattr, gcW, gcatl, rbuf, bu, bx2, gcb, off, perm, bh);
  k_gru<<<NND/32,256,0,stream>>>(bh, x0, xh, g0Wib, g0Whb, g0bi, g0bh);

  // atom GAT layers
  for(int l=0;l<2;l++){
    k_gemm<4,4,false,false,0,true><<<GB,256,0,stream>>>(xh, H, aWb + (size_t)l*HH, nullptr, bu, NND);
    k_rowdot<true,true><<<25000,256,0,stream>>>(bu, aas + l*H, aad + l*H, s1, s2, NND);
    k_atom_agg<<<25000,256,0,stream>>>(ei, s1, s2, bu, ab + l*H, off, perm, bh);
    k_gru<<<NND/32,256,0,stream>>>(bh, xh, xh, agWib + (size_t)l*H3H, agWhb + (size_t)l*H3H,
                                   agbi + l*3*H, agbh + l*3*H);
  }

  // molecule readout
  k_seg0<<<NG/4,256,0,stream>>>(xh, goff, outg);
  k_gemm<4,4,false,false,0,true><<<GB,256,0,stream>>>(xh, H, mWb, nullptr, xm, NND);
  k_rowdot<true,false><<<25000,256,0,stream>>>(xm, mas, nullptr, asrc, nullptr, NND);
  for(int t=0;t<2;t++){
    k_gemm<4,4,false,false,0,false><<<(NG+63)/64,256,0,stream>>>(outg, H, mWb, nullptr, om, NG);
    k_rowdot<false,false><<<NG/4,256,0,stream>>>(om, mad, nullptr, dgb, nullptr, NG);
    k_mol_agg<<<NG/4,256,0,stream>>>(asrc, dgb, xm, goff, mb, hmol);
    k_gru<<<NG/32,256,0,stream>>>(hmol, outg, outg, mgWib, mgWhb, mgbi, mgbh);
  }

  // head
  k_gemm<4,4,false,true,0,false><<<(NG+63)/64,256,0,stream>>>(outg, H, l2Wb, l2b, emb, NG);
  k_cls<<<NG/4,256,0,stream>>>(emb, cW1, cb1, cW2, cb2, outp);
}